// Round 1
// baseline (2612.107 us; speedup 1.0000x reference)
//
#include <hip/hip_runtime.h>
#include <hip/hip_bf16.h>

#define B_ 4
#define N_ 1024
#define D_ 1024
#define H_ 16
#define DH_ 64
#define E_ 2112
#define ROWS_ 4096

typedef __bf16 bf16_t;
typedef bf16_t bf16x4 __attribute__((ext_vector_type(4)));
typedef bf16_t bf16x8 __attribute__((ext_vector_type(8)));
typedef float f32x4 __attribute__((ext_vector_type(4)));

// ---------------------------------------------------------------------------
// Phase 1: y = x @ Wkqv[h] + bkqv[h]  (per-head GEMM, fp32 in, bf16 out)
// split columns: [0,1024) -> K, [1024,2048) -> Q, [2048,2112) -> V
// BM=128, BN=128, BK=64. 4 waves in 2x2, wave tile 64x64, mfma 16x16x32 bf16.
// ---------------------------------------------------------------------------
__global__ __launch_bounds__(256)
void kqv_gemm(const float* __restrict__ x, const float* __restrict__ Wkqv,
              const float* __restrict__ bkqv,
              bf16_t* __restrict__ Kt, bf16_t* __restrict__ Qt,
              bf16_t* __restrict__ Vg) {
  const int mb = blockIdx.x, nb = blockIdx.y, h = blockIdx.z;
  const int t = threadIdx.x;
  const int w = t >> 6, l = t & 63, l15 = l & 15, lg = l >> 4;
  const int wr = (w >> 1) * 64, wc = (w & 1) * 64;

  __shared__ bf16_t xs[128][72];       // A tile, +8 pad (2-way banks = free)
  __shared__ bf16_t wl[8][128][8];     // B tile in frag-native layout [k>>3][col][k&7]

  const float* Wh = Wkqv + (size_t)h * D_ * E_;
  f32x4 acc[4][4] = {};

  for (int kb = 0; kb < 16; ++kb) {
    __syncthreads();
    // stage x tile 128x64 (fp32 -> bf16)
    #pragma unroll
    for (int i = 0; i < 8; ++i) {
      int flat = t + i * 256;               // float4 units, 2048 total
      int row = flat >> 4, c4 = (flat & 15) << 2;
      float4 v = *(const float4*)(x + (size_t)(mb * 128 + row) * D_ + kb * 64 + c4);
      bf16x4 bv = {(bf16_t)v.x, (bf16_t)v.y, (bf16_t)v.z, (bf16_t)v.w};
      *(bf16x4*)(&xs[row][c4]) = bv;
    }
    // stage W tile 64x128 (fp32 -> bf16) into frag layout; guard col tail
    #pragma unroll
    for (int i = 0; i < 8; ++i) {
      int flat = t + i * 256;
      int row = flat >> 5, c4 = (flat & 31) << 2;
      int gc = nb * 128 + c4;
      float4 v = {0.f, 0.f, 0.f, 0.f};
      if (gc < E_) v = *(const float4*)(Wh + (size_t)(kb * 64 + row) * E_ + gc);
      wl[row >> 3][c4 + 0][row & 7] = (bf16_t)v.x;
      wl[row >> 3][c4 + 1][row & 7] = (bf16_t)v.y;
      wl[row >> 3][c4 + 2][row & 7] = (bf16_t)v.z;
      wl[row >> 3][c4 + 3][row & 7] = (bf16_t)v.w;
    }
    __syncthreads();
    #pragma unroll
    for (int ks = 0; ks < 2; ++ks) {
      bf16x8 a[4], bb[4];
      #pragma unroll
      for (int mi = 0; mi < 4; ++mi)
        a[mi] = *(const bf16x8*)(&xs[wr + mi * 16 + l15][ks * 32 + lg * 8]);
      #pragma unroll
      for (int ni = 0; ni < 4; ++ni)
        bb[ni] = *(const bf16x8*)(&wl[ks * 4 + lg][wc + ni * 16 + l15][0]);
      #pragma unroll
      for (int mi = 0; mi < 4; ++mi)
        #pragma unroll
        for (int ni = 0; ni < 4; ++ni)
          acc[mi][ni] = __builtin_amdgcn_mfma_f32_16x16x32_bf16(a[mi], bb[ni], acc[mi][ni], 0, 0, 0);
    }
  }

  // epilogue: bias add, split-store bf16
  #pragma unroll
  for (int ni = 0; ni < 4; ++ni) {
    int e = nb * 128 + wc + ni * 16 + l15;
    if (e < E_) {
      float bias = bkqv[h * E_ + e];
      #pragma unroll
      for (int mi = 0; mi < 4; ++mi) {
        #pragma unroll
        for (int r = 0; r < 4; ++r) {
          int grow = mb * 128 + wr + mi * 16 + lg * 4 + r;
          float val = acc[mi][ni][r] + bias;
          bf16_t bv = (bf16_t)val;
          int b = grow >> 10, n = grow & (N_ - 1);
          size_t bh = (size_t)(b * H_ + h);
          if (e < D_)
            Kt[(bh * N_ + n) * D_ + e] = bv;
          else if (e < 2 * D_)
            Qt[(bh * N_ + n) * D_ + (e - D_)] = bv;
          else
            Vg[(bh * N_ + n) * DH_ + (e - 2 * D_)] = bv;
        }
      }
    }
  }
}

// ---------------------------------------------------------------------------
// Phase 2: flash attention per (b,h,q-tile=64). d_qk = 1024, d_v = 64.
// 4 waves, wave owns 16 q-rows. Q/K frags straight from global (L2-hot).
// Online softmax in exp2 domain; P via padded LDS; V transposed in LDS.
// ---------------------------------------------------------------------------
__global__ __launch_bounds__(256)
void attn_kernel(const bf16_t* __restrict__ Kt, const bf16_t* __restrict__ Qt,
                 const bf16_t* __restrict__ Vg, bf16_t* __restrict__ sa) {
  const int qt = blockIdx.x;   // 0..15
  const int bh = blockIdx.y;   // 0..63  (= b*16 + h)
  const int t = threadIdx.x;
  const int w = t >> 6, l = t & 63, l15 = l & 15, lg = l >> 4;
  const int qb = qt * 64;
  const bf16_t* Qh = Qt + (size_t)bh * N_ * D_;
  const bf16_t* Kh = Kt + (size_t)bh * N_ * D_;
  const bf16_t* Vh = Vg + (size_t)bh * N_ * DH_;

  __shared__ bf16_t vt[DH_][72];      // V^T tile: vt[dh][kv]
  __shared__ bf16_t pl[4][16][72];    // per-wave P tile [qrow16][kv64]

  f32x4 acc_o[4] = {};
  float m_r[4], l_r[4];
  #pragma unroll
  for (int r = 0; r < 4; ++r) { m_r[r] = -1e30f; l_r[r] = 0.f; }

  const float SCALE = 0.045084220027780106f;   // log2(e) / sqrt(1024)
  const int qrowA = qb + w * 16 + l15;         // A-frag q-row for this lane

  for (int j = 0; j <= qt; ++j) {
    const int jb = j * 64;
    __syncthreads();                           // protect vt from prev-iter readers
    for (int i = t; i < 64 * 64; i += 256) {   // stage V^T
      int kv = i >> 6, dh = i & 63;
      vt[dh][kv] = Vh[(size_t)(jb + kv) * DH_ + dh];
    }

    // S = Q . K^T  (16 q-rows x 64 kv per wave), K-dim 1024 in 32 steps
    f32x4 s[4] = {};
    #pragma unroll 4
    for (int kc = 0; kc < 32; ++kc) {
      bf16x8 a = *(const bf16x8*)(Qh + (size_t)qrowA * D_ + kc * 32 + lg * 8);
      #pragma unroll
      for (int cb = 0; cb < 4; ++cb) {
        bf16x8 bk = *(const bf16x8*)(Kh + (size_t)(jb + cb * 16 + l15) * D_ + kc * 32 + lg * 8);
        s[cb] = __builtin_amdgcn_mfma_f32_16x16x32_bf16(a, bk, s[cb], 0, 0, 0);
      }
    }
    __syncthreads();                           // vt ready

    // scale + causal mask (diagonal tile only)
    float z[4][4];
    #pragma unroll
    for (int cb = 0; cb < 4; ++cb) {
      int col = jb + cb * 16 + l15;
      #pragma unroll
      for (int r = 0; r < 4; ++r) {
        float zz = s[cb][r] * SCALE;
        if (j == qt && col > qb + w * 16 + lg * 4 + r) zz = -1e30f;
        z[cb][r] = zz;
      }
    }
    // online softmax per q-row (row spread over 16 lanes + 4 in-lane cols)
    #pragma unroll
    for (int r = 0; r < 4; ++r) {
      float rm = fmaxf(fmaxf(z[0][r], z[1][r]), fmaxf(z[2][r], z[3][r]));
      rm = fmaxf(rm, __shfl_xor(rm, 1));
      rm = fmaxf(rm, __shfl_xor(rm, 2));
      rm = fmaxf(rm, __shfl_xor(rm, 4));
      rm = fmaxf(rm, __shfl_xor(rm, 8));
      float mnew = fmaxf(m_r[r], rm);
      float scl = exp2f(m_r[r] - mnew);
      m_r[r] = mnew;
      float rs = 0.f;
      #pragma unroll
      for (int cb = 0; cb < 4; ++cb) {
        float p = exp2f(z[cb][r] - mnew);
        rs += p;
        pl[w][lg * 4 + r][cb * 16 + l15] = (bf16_t)p;
      }
      rs += __shfl_xor(rs, 1);
      rs += __shfl_xor(rs, 2);
      rs += __shfl_xor(rs, 4);
      rs += __shfl_xor(rs, 8);
      l_r[r] = l_r[r] * scl + rs;
      #pragma unroll
      for (int db = 0; db < 4; ++db) acc_o[db][r] *= scl;
    }

    // O += P . V   (P from wave-private LDS, V^T from shared LDS)
    #pragma unroll
    for (int ks = 0; ks < 2; ++ks) {
      bf16x8 pa = *(const bf16x8*)(&pl[w][l15][ks * 32 + lg * 8]);
      #pragma unroll
      for (int db = 0; db < 4; ++db) {
        bf16x8 vb = *(const bf16x8*)(&vt[db * 16 + l15][ks * 32 + lg * 8]);
        acc_o[db] = __builtin_amdgcn_mfma_f32_16x16x32_bf16(pa, vb, acc_o[db], 0, 0, 0);
      }
    }
  }

  const int b = bh >> 4, h = bh & 15;
  #pragma unroll
  for (int db = 0; db < 4; ++db) {
    #pragma unroll
    for (int r = 0; r < 4; ++r) {
      float o = acc_o[db][r] / l_r[r];
      int row = qb + w * 16 + lg * 4 + r;
      int col = h * DH_ + db * 16 + l15;
      sa[((size_t)b * N_ + row) * D_ + col] = (bf16_t)o;
    }
  }
}

// ---------------------------------------------------------------------------
// Phase 3: out = sa @ Wp + bp   (bf16 A, fp32->bf16 B, fp32 out)
// ---------------------------------------------------------------------------
__global__ __launch_bounds__(256)
void out_gemm(const bf16_t* __restrict__ sa, const float* __restrict__ Wp,
              const float* __restrict__ bp, float* __restrict__ out) {
  const int mb = blockIdx.x, nb = blockIdx.y;
  const int t = threadIdx.x;
  const int w = t >> 6, l = t & 63, l15 = l & 15, lg = l >> 4;
  const int wr = (w >> 1) * 64, wc = (w & 1) * 64;

  __shared__ bf16_t xs[128][72];
  __shared__ bf16_t wl[8][128][8];

  f32x4 acc[4][4] = {};

  for (int kb = 0; kb < 16; ++kb) {
    __syncthreads();
    #pragma unroll
    for (int i = 0; i < 8; ++i) {
      int flat = t + i * 256;                  // bf16x4 units, 2048 total
      int row = flat >> 4, c4 = (flat & 15) << 2;
      *(bf16x4*)(&xs[row][c4]) =
          *(const bf16x4*)(sa + (size_t)(mb * 128 + row) * D_ + kb * 64 + c4);
    }
    #pragma unroll
    for (int i = 0; i < 8; ++i) {
      int flat = t + i * 256;
      int row = flat >> 5, c4 = (flat & 31) << 2;
      float4 v = *(const float4*)(Wp + (size_t)(kb * 64 + row) * D_ + nb * 128 + c4);
      wl[row >> 3][c4 + 0][row & 7] = (bf16_t)v.x;
      wl[row >> 3][c4 + 1][row & 7] = (bf16_t)v.y;
      wl[row >> 3][c4 + 2][row & 7] = (bf16_t)v.z;
      wl[row >> 3][c4 + 3][row & 7] = (bf16_t)v.w;
    }
    __syncthreads();
    #pragma unroll
    for (int ks = 0; ks < 2; ++ks) {
      bf16x8 a[4], bb[4];
      #pragma unroll
      for (int mi = 0; mi < 4; ++mi)
        a[mi] = *(const bf16x8*)(&xs[wr + mi * 16 + l15][ks * 32 + lg * 8]);
      #pragma unroll
      for (int ni = 0; ni < 4; ++ni)
        bb[ni] = *(const bf16x8*)(&wl[ks * 4 + lg][wc + ni * 16 + l15][0]);
      #pragma unroll
      for (int mi = 0; mi < 4; ++mi)
        #pragma unroll
        for (int ni = 0; ni < 4; ++ni)
          acc[mi][ni] = __builtin_amdgcn_mfma_f32_16x16x32_bf16(a[mi], bb[ni], acc[mi][ni], 0, 0, 0);
    }
  }

  #pragma unroll
  for (int ni = 0; ni < 4; ++ni) {
    int e = nb * 128 + wc + ni * 16 + l15;
    float bias = bp[e];
    #pragma unroll
    for (int mi = 0; mi < 4; ++mi) {
      #pragma unroll
      for (int r = 0; r < 4; ++r) {
        int grow = mb * 128 + wr + mi * 16 + lg * 4 + r;
        out[(size_t)grow * D_ + e] = acc[mi][ni][r] + bias;
      }
    }
  }
}

// ---------------------------------------------------------------------------
extern "C" void kernel_launch(void* const* d_in, const int* in_sizes, int n_in,
                              void* d_out, int out_size, void* d_ws, size_t ws_size,
                              hipStream_t stream) {
  const float* x    = (const float*)d_in[0];
  const float* Wkqv = (const float*)d_in[1];
  const float* bkqv = (const float*)d_in[2];
  const float* Wp   = (const float*)d_in[3];
  const float* bp   = (const float*)d_in[4];
  float* out = (float*)d_out;

  char* ws = (char*)d_ws;
  const size_t SZ_KQ = (size_t)B_ * H_ * N_ * D_ * sizeof(bf16_t);   // 128 MiB
  const size_t SZ_V  = (size_t)B_ * H_ * N_ * DH_ * sizeof(bf16_t);  // 8 MiB
  bf16_t* Kt = (bf16_t*)ws;
  bf16_t* Qt = (bf16_t*)(ws + SZ_KQ);
  bf16_t* Vg = (bf16_t*)(ws + 2 * SZ_KQ);
  bf16_t* sa = (bf16_t*)(ws + 2 * SZ_KQ + SZ_V);
  // total workspace use: 2*134217728 + 8388608 + 8388608 = 285,212,672 B

  hipLaunchKernelGGL(kqv_gemm, dim3(32, 17, 16), dim3(256), 0, stream,
                     x, Wkqv, bkqv, Kt, Qt, Vg);
  hipLaunchKernelGGL(attn_kernel, dim3(16, 64), dim3(256), 0, stream,
                     Kt, Qt, Vg, sa);
  hipLaunchKernelGGL(out_gemm, dim3(32, 8), dim3(256), 0, stream,
                     sa, Wp, bp, out);
}

// Round 2
// 883.976 us; speedup vs baseline: 2.9550x; 2.9550x over previous
//
#include <hip/hip_runtime.h>
#include <hip/hip_bf16.h>

#define B_ 4
#define N_ 1024
#define D_ 1024
#define H_ 16
#define DH_ 64
#define E_ 2112
#define EP_ 2176
#define ROWS_ 4096

typedef __bf16 bf16_t;
typedef bf16_t bf16x4 __attribute__((ext_vector_type(4)));
typedef bf16_t bf16x8 __attribute__((ext_vector_type(8)));
typedef float f32x4 __attribute__((ext_vector_type(4)));

__device__ __forceinline__ void gload_lds16(const void* g, void* l) {
  __builtin_amdgcn_global_load_lds(
      (const __attribute__((address_space(1))) void*)g,
      (__attribute__((address_space(3))) void*)l, 16, 0, 0);
}

// ---------------------------------------------------------------------------
// conversion passes
// ---------------------------------------------------------------------------
__global__ __launch_bounds__(256)
void conv_x(const float* __restrict__ x, bf16_t* __restrict__ xb) {
  const int n4 = ROWS_ * D_ / 4;
  for (int i = blockIdx.x * 256 + threadIdx.x; i < n4; i += gridDim.x * 256) {
    float4 v = ((const float4*)x)[i];
    bf16x4 o = {(bf16_t)v.x, (bf16_t)v.y, (bf16_t)v.z, (bf16_t)v.w};
    ((bf16x4*)xb)[i] = o;
  }
}

// W[h][d][e] fp32  ->  Wt[hz][e][d] bf16, e padded to EP_ with zeros
__global__ __launch_bounds__(256)
void conv_wkqv(const float* __restrict__ W, bf16_t* __restrict__ Wt, int h0) {
  const int et = blockIdx.x, dt = blockIdx.y, hz = blockIdx.z;
  const int h = h0 + hz;
  const int tx = threadIdx.x & 31, ty = threadIdx.x >> 5;
  __shared__ float tile[32][33];
  const float* Wh = W + (size_t)h * D_ * E_;
  #pragma unroll
  for (int rr = 0; rr < 4; ++rr) {
    int d = dt * 32 + rr * 8 + ty;
    int e = et * 32 + tx;
    tile[rr * 8 + ty][tx] = (e < E_) ? Wh[(size_t)d * E_ + e] : 0.f;
  }
  __syncthreads();
  bf16_t* Wto = Wt + (size_t)hz * EP_ * D_;
  #pragma unroll
  for (int rr = 0; rr < 4; ++rr) {
    int e = et * 32 + rr * 8 + ty;
    int d = dt * 32 + tx;
    Wto[(size_t)e * D_ + d] = (bf16_t)tile[tx][rr * 8 + ty];
  }
}

// Wp[k][n] fp32 -> Wpt[n][k] bf16
__global__ __launch_bounds__(256)
void conv_wp(const float* __restrict__ Wp, bf16_t* __restrict__ Wpt) {
  const int nt = blockIdx.x, kt = blockIdx.y;
  const int tx = threadIdx.x & 31, ty = threadIdx.x >> 5;
  __shared__ float tile[32][33];
  #pragma unroll
  for (int rr = 0; rr < 4; ++rr)
    tile[rr * 8 + ty][tx] = Wp[(size_t)(kt * 32 + rr * 8 + ty) * D_ + nt * 32 + tx];
  __syncthreads();
  #pragma unroll
  for (int rr = 0; rr < 4; ++rr)
    Wpt[(size_t)(nt * 32 + rr * 8 + ty) * D_ + kt * 32 + tx] = (bf16_t)tile[tx][rr * 8 + ty];
}

// ---------------------------------------------------------------------------
// Phase 1: y = x @ Wkqv[h] + b  (bf16 A [4096][1024], bf16 B^T [EP_][1024])
// m97 structure: 128x128 tile, BK=64, global_load_lds width 16, 2 barriers.
// K -> Kg[bh][n][d], Q -> Qg[bh][n][d], V -> Vt[bh][dh][n] (transposed!)
// ---------------------------------------------------------------------------
__global__ __launch_bounds__(256)
void kqv_gemm(const bf16_t* __restrict__ A, const bf16_t* __restrict__ Wt,
              const float* __restrict__ bkqv, int h0,
              bf16_t* __restrict__ Kg, bf16_t* __restrict__ Qg,
              bf16_t* __restrict__ Vt) {
  const int mb = blockIdx.x, nb = blockIdx.y, hz = blockIdx.z;
  const int h = h0 + hz;
  const int t = threadIdx.x;
  const int w = t >> 6, l = t & 63, l15 = l & 15, lg = l >> 4;
  const int wr = (w >> 1) * 64, wc = (w & 1) * 64;

  __shared__ bf16_t As[128 * 64];
  __shared__ bf16_t Bs[128 * 64];
  const bf16_t* Bh = Wt + (size_t)hz * EP_ * D_;

  const int srow = w * 32 + (l >> 3);
  const int scol = (l & 7) * 8;
  const bf16_t* ag = A + (size_t)(mb * 128 + srow) * D_ + scol;
  const bf16_t* bg = Bh + (size_t)(nb * 128 + srow) * D_ + scol;
  char* asl = (char*)As + w * 4096;
  char* bsl = (char*)Bs + w * 4096;

  f32x4 acc[4][4] = {};

  for (int kb = 0; kb < 16; ++kb) {
    __syncthreads();
    #pragma unroll
    for (int i = 0; i < 4; ++i) {
      gload_lds16(ag + (size_t)i * 8 * D_ + kb * 64, asl + i * 1024);
      gload_lds16(bg + (size_t)i * 8 * D_ + kb * 64, bsl + i * 1024);
    }
    __syncthreads();
    #pragma unroll
    for (int ks = 0; ks < 2; ++ks) {
      bf16x8 a[4], b[4];
      #pragma unroll
      for (int mi = 0; mi < 4; ++mi)
        a[mi] = *(const bf16x8*)((const char*)As + (wr + mi * 16 + l15) * 128 + ks * 64 + lg * 16);
      #pragma unroll
      for (int ni = 0; ni < 4; ++ni)
        b[ni] = *(const bf16x8*)((const char*)Bs + (wc + ni * 16 + l15) * 128 + ks * 64 + lg * 16);
      #pragma unroll
      for (int mi = 0; mi < 4; ++mi)
        #pragma unroll
        for (int ni = 0; ni < 4; ++ni)
          acc[mi][ni] = __builtin_amdgcn_mfma_f32_16x16x32_bf16(a[mi], b[ni], acc[mi][ni], 0, 0, 0);
    }
  }

  #pragma unroll
  for (int ni = 0; ni < 4; ++ni) {
    int e = nb * 128 + wc + ni * 16 + l15;
    if (e < E_) {
      float bias = bkqv[h * E_ + e];
      #pragma unroll
      for (int mi = 0; mi < 4; ++mi) {
        #pragma unroll
        for (int r = 0; r < 4; ++r) {
          int grow = mb * 128 + wr + mi * 16 + lg * 4 + r;
          bf16_t bv = (bf16_t)(acc[mi][ni][r] + bias);
          int b = grow >> 10, n = grow & (N_ - 1);
          size_t bh = (size_t)(b * H_ + h);
          if (e < D_)
            Kg[(bh * N_ + n) * D_ + e] = bv;
          else if (e < 2 * D_)
            Qg[(bh * N_ + n) * D_ + (e - D_)] = bv;
          else
            Vt[(bh * DH_ + (e - 2 * D_)) * N_ + n] = bv;
        }
      }
    }
  }
}

// ---------------------------------------------------------------------------
// Phase 2: flash attention. QBLK=128 (4 waves x 32 rows), KVBLK=64, d in 16
// chunks of 64 staged via global_load_lds. V^T staged linearly (pre-transposed).
// ---------------------------------------------------------------------------
__global__ __launch_bounds__(256)
void attn_kernel(const bf16_t* __restrict__ Kg, const bf16_t* __restrict__ Qg,
                 const bf16_t* __restrict__ Vtg, bf16_t* __restrict__ sa) {
  const int qt = blockIdx.x;   // 0..7
  const int bh = blockIdx.y;   // 0..63
  const int t = threadIdx.x;
  const int w = t >> 6, l = t & 63, l15 = l & 15, lg = l >> 4;
  const int qb = qt * 128;
  const int wrow = w * 32;
  const bf16_t* Qh = Qg + (size_t)bh * N_ * D_;
  const bf16_t* Kh = Kg + (size_t)bh * N_ * D_;
  const bf16_t* Vh = Vtg + (size_t)bh * DH_ * N_;

  __shared__ bf16_t Qs[128 * 64];
  __shared__ bf16_t Ks[64 * 64];
  __shared__ bf16_t Vs[64 * 64];      // Vs[dh][kv]
  __shared__ bf16_t Ps[4][32][72];

  f32x4 accO[2][4] = {};
  float m_r[2][4], l_r[2][4];
  #pragma unroll
  for (int mi = 0; mi < 2; ++mi)
    #pragma unroll
    for (int r = 0; r < 4; ++r) { m_r[mi][r] = -1e30f; l_r[mi][r] = 0.f; }

  const float SCALE = 0.045084220027780106f;   // log2(e)/sqrt(1024)
  const int srow = (l >> 3), scol = (l & 7) * 8;
  char* qsl = (char*)Qs + w * 4096;
  char* ksl = (char*)Ks + w * 2048;
  char* vsl = (char*)Vs + w * 2048;

  const int nj = 2 * qt + 2;
  for (int j = 0; j < nj; ++j) {
    const int jb = j * 64;
    f32x4 s[2][4] = {};
    for (int dc = 0; dc < 16; ++dc) {
      __syncthreads();
      #pragma unroll
      for (int i = 0; i < 4; ++i)
        gload_lds16(Qh + (size_t)(qb + w * 32 + i * 8 + srow) * D_ + dc * 64 + scol,
                    qsl + i * 1024);
      #pragma unroll
      for (int i = 0; i < 2; ++i)
        gload_lds16(Kh + (size_t)(jb + w * 16 + i * 8 + srow) * D_ + dc * 64 + scol,
                    ksl + i * 1024);
      __syncthreads();
      #pragma unroll
      for (int ks = 0; ks < 2; ++ks) {
        bf16x8 a[2], b[4];
        #pragma unroll
        for (int mi = 0; mi < 2; ++mi)
          a[mi] = *(const bf16x8*)((const char*)Qs + (wrow + mi * 16 + l15) * 128 + ks * 64 + lg * 16);
        #pragma unroll
        for (int ni = 0; ni < 4; ++ni)
          b[ni] = *(const bf16x8*)((const char*)Ks + (ni * 16 + l15) * 128 + ks * 64 + lg * 16);
        #pragma unroll
        for (int mi = 0; mi < 2; ++mi)
          #pragma unroll
          for (int ni = 0; ni < 4; ++ni)
            s[mi][ni] = __builtin_amdgcn_mfma_f32_16x16x32_bf16(a[mi], b[ni], s[mi][ni], 0, 0, 0);
      }
    }
    // stage V^T for this j (consumed after the next barrier)
    #pragma unroll
    for (int i = 0; i < 2; ++i)
      gload_lds16(Vh + (size_t)(w * 16 + i * 8 + srow) * N_ + jb + scol, vsl + i * 1024);

    // mask + scale + online softmax
    #pragma unroll
    for (int mi = 0; mi < 2; ++mi) {
      float z[4][4];
      #pragma unroll
      for (int ni = 0; ni < 4; ++ni) {
        int col = jb + ni * 16 + l15;
        #pragma unroll
        for (int r = 0; r < 4; ++r) {
          int row = qb + wrow + mi * 16 + lg * 4 + r;
          float zz = s[mi][ni][r] * SCALE;
          if (col > row) zz = -1e30f;
          z[ni][r] = zz;
        }
      }
      #pragma unroll
      for (int r = 0; r < 4; ++r) {
        float rm = fmaxf(fmaxf(z[0][r], z[1][r]), fmaxf(z[2][r], z[3][r]));
        rm = fmaxf(rm, __shfl_xor(rm, 1));
        rm = fmaxf(rm, __shfl_xor(rm, 2));
        rm = fmaxf(rm, __shfl_xor(rm, 4));
        rm = fmaxf(rm, __shfl_xor(rm, 8));
        float mnew = fmaxf(m_r[mi][r], rm);
        float scl = exp2f(m_r[mi][r] - mnew);
        m_r[mi][r] = mnew;
        float rs = 0.f;
        #pragma unroll
        for (int ni = 0; ni < 4; ++ni) {
          float p = exp2f(z[ni][r] - mnew);
          rs += p;
          Ps[w][mi * 16 + lg * 4 + r][ni * 16 + l15] = (bf16_t)p;
        }
        rs += __shfl_xor(rs, 1);
        rs += __shfl_xor(rs, 2);
        rs += __shfl_xor(rs, 4);
        rs += __shfl_xor(rs, 8);
        l_r[mi][r] = l_r[mi][r] * scl + rs;
        #pragma unroll
        for (int ni = 0; ni < 4; ++ni) accO[mi][ni][r] *= scl;
      }
    }
    __syncthreads();   // Vs staged + all waves done with softmax

    // O += P . V
    #pragma unroll
    for (int ks = 0; ks < 2; ++ks) {
      bf16x8 pa[2];
      #pragma unroll
      for (int mi = 0; mi < 2; ++mi)
        pa[mi] = *(const bf16x8*)(&Ps[w][mi * 16 + l15][ks * 32 + lg * 8]);
      #pragma unroll
      for (int ni = 0; ni < 4; ++ni) {
        bf16x8 vb = *(const bf16x8*)((const char*)Vs + (ni * 16 + l15) * 128 + ks * 64 + lg * 16);
        #pragma unroll
        for (int mi = 0; mi < 2; ++mi)
          accO[mi][ni] = __builtin_amdgcn_mfma_f32_16x16x32_bf16(pa[mi], vb, accO[mi][ni], 0, 0, 0);
      }
    }
  }

  const int b = bh >> 4, h = bh & 15;
  #pragma unroll
  for (int mi = 0; mi < 2; ++mi)
    #pragma unroll
    for (int ni = 0; ni < 4; ++ni)
      #pragma unroll
      for (int r = 0; r < 4; ++r) {
        int row = qb + wrow + mi * 16 + lg * 4 + r;
        int col = h * DH_ + ni * 16 + l15;
        sa[((size_t)b * N_ + row) * D_ + col] = (bf16_t)(accO[mi][ni][r] / l_r[mi][r]);
      }
}

// ---------------------------------------------------------------------------
// Phase 3: out = sa @ Wp + bp   (m97 structure, fp32 out)
// ---------------------------------------------------------------------------
__global__ __launch_bounds__(256)
void out_gemm(const bf16_t* __restrict__ A, const bf16_t* __restrict__ Bt,
              const float* __restrict__ bp, float* __restrict__ out) {
  const int mb = blockIdx.x, nb = blockIdx.y;
  const int t = threadIdx.x;
  const int w = t >> 6, l = t & 63, l15 = l & 15, lg = l >> 4;
  const int wr = (w >> 1) * 64, wc = (w & 1) * 64;

  __shared__ bf16_t As[128 * 64];
  __shared__ bf16_t Bs[128 * 64];

  const int srow = w * 32 + (l >> 3);
  const int scol = (l & 7) * 8;
  const bf16_t* ag = A + (size_t)(mb * 128 + srow) * D_ + scol;
  const bf16_t* bg = Bt + (size_t)(nb * 128 + srow) * D_ + scol;
  char* asl = (char*)As + w * 4096;
  char* bsl = (char*)Bs + w * 4096;

  f32x4 acc[4][4] = {};

  for (int kb = 0; kb < 16; ++kb) {
    __syncthreads();
    #pragma unroll
    for (int i = 0; i < 4; ++i) {
      gload_lds16(ag + (size_t)i * 8 * D_ + kb * 64, asl + i * 1024);
      gload_lds16(bg + (size_t)i * 8 * D_ + kb * 64, bsl + i * 1024);
    }
    __syncthreads();
    #pragma unroll
    for (int ks = 0; ks < 2; ++ks) {
      bf16x8 a[4], b[4];
      #pragma unroll
      for (int mi = 0; mi < 4; ++mi)
        a[mi] = *(const bf16x8*)((const char*)As + (wr + mi * 16 + l15) * 128 + ks * 64 + lg * 16);
      #pragma unroll
      for (int ni = 0; ni < 4; ++ni)
        b[ni] = *(const bf16x8*)((const char*)Bs + (wc + ni * 16 + l15) * 128 + ks * 64 + lg * 16);
      #pragma unroll
      for (int mi = 0; mi < 4; ++mi)
        #pragma unroll
        for (int ni = 0; ni < 4; ++ni)
          acc[mi][ni] = __builtin_amdgcn_mfma_f32_16x16x32_bf16(a[mi], b[ni], acc[mi][ni], 0, 0, 0);
    }
  }

  #pragma unroll
  for (int ni = 0; ni < 4; ++ni) {
    int e = nb * 128 + wc + ni * 16 + l15;
    float bias = bp[e];
    #pragma unroll
    for (int mi = 0; mi < 4; ++mi)
      #pragma unroll
      for (int r = 0; r < 4; ++r) {
        int grow = mb * 128 + wr + mi * 16 + lg * 4 + r;
        out[(size_t)grow * D_ + e] = acc[mi][ni][r] + bias;
      }
  }
}

// ---------------------------------------------------------------------------
extern "C" void kernel_launch(void* const* d_in, const int* in_sizes, int n_in,
                              void* d_out, int out_size, void* d_ws, size_t ws_size,
                              hipStream_t stream) {
  const float* x    = (const float*)d_in[0];
  const float* Wkqv = (const float*)d_in[1];
  const float* bkqv = (const float*)d_in[2];
  const float* Wp   = (const float*)d_in[3];
  const float* bp   = (const float*)d_in[4];
  float* out = (float*)d_out;
  char* ws = (char*)d_ws;

  const size_t SZ_QK  = (size_t)B_ * H_ * N_ * D_ * 2;   // 128 MiB each
  const size_t SZ_V   = (size_t)B_ * H_ * DH_ * N_ * 2;  // 8 MiB
  const size_t SZ_XB  = (size_t)ROWS_ * D_ * 2;          // 8 MiB (also sa)
  const size_t SZ_WPT = (size_t)D_ * D_ * 2;             // 2 MiB
  const size_t SZ_WT1 = (size_t)EP_ * D_ * 2;            // per-head Wt

  bf16_t* Qg  = (bf16_t*)(ws);
  bf16_t* Kg  = (bf16_t*)(ws + SZ_QK);
  bf16_t* Vt  = (bf16_t*)(ws + 2 * SZ_QK);
  bf16_t* xb  = (bf16_t*)(ws + 2 * SZ_QK + SZ_V);        // sa aliases xb
  bf16_t* sa  = xb;
  bf16_t* Wpt = (bf16_t*)(ws + 2 * SZ_QK + SZ_V + SZ_XB);
  bf16_t* Wt  = (bf16_t*)(ws + 2 * SZ_QK + SZ_V + SZ_XB + SZ_WPT);

  const size_t FULL_NEED = 2 * SZ_QK + SZ_V + SZ_XB + SZ_WPT + 16 * SZ_WT1;

  hipLaunchKernelGGL(conv_x, dim3(1024), dim3(256), 0, stream, x, xb);
  hipLaunchKernelGGL(conv_wp, dim3(32, 32), dim3(256), 0, stream, Wp, Wpt);

  if (ws_size >= FULL_NEED) {
    hipLaunchKernelGGL(conv_wkqv, dim3(68, 32, 16), dim3(256), 0, stream, Wkqv, Wt, 0);
    hipLaunchKernelGGL(kqv_gemm, dim3(32, 17, 16), dim3(256), 0, stream,
                       xb, Wt, bkqv, 0, Kg, Qg, Vt);
  } else {
    for (int h = 0; h < H_; ++h) {
      hipLaunchKernelGGL(conv_wkqv, dim3(68, 32, 1), dim3(256), 0, stream, Wkqv, Wt, h);
      hipLaunchKernelGGL(kqv_gemm, dim3(32, 17, 1), dim3(256), 0, stream,
                         xb, Wt, bkqv, h, Kg, Qg, Vt);
    }
  }

  hipLaunchKernelGGL(attn_kernel, dim3(8, 64), dim3(256), 0, stream, Kg, Qg, Vt, sa);
  hipLaunchKernelGGL(out_gemm, dim3(32, 8), dim3(256), 0, stream, sa, Wpt, bp, out);
}

// Round 3
// 829.643 us; speedup vs baseline: 3.1485x; 1.0655x over previous
//
#include <hip/hip_runtime.h>
#include <hip/hip_bf16.h>

#define B_ 4
#define N_ 1024
#define D_ 1024
#define H_ 16
#define DH_ 64
#define E_ 2112
#define EP_ 2176
#define ROWS_ 4096

typedef __bf16 bf16_t;
typedef bf16_t bf16x4 __attribute__((ext_vector_type(4)));
typedef bf16_t bf16x8 __attribute__((ext_vector_type(8)));
typedef float f32x4 __attribute__((ext_vector_type(4)));

__device__ __forceinline__ void gload_lds16(const void* g, void* l) {
  __builtin_amdgcn_global_load_lds(
      (const __attribute__((address_space(1))) void*)g,
      (__attribute__((address_space(3))) void*)l, 16, 0, 0);
}

// ---------------------------------------------------------------------------
// conversion passes
// ---------------------------------------------------------------------------
__global__ __launch_bounds__(256)
void conv_x(const float* __restrict__ x, bf16_t* __restrict__ xb) {
  const int n4 = ROWS_ * D_ / 4;
  for (int i = blockIdx.x * 256 + threadIdx.x; i < n4; i += gridDim.x * 256) {
    float4 v = ((const float4*)x)[i];
    bf16x4 o = {(bf16_t)v.x, (bf16_t)v.y, (bf16_t)v.z, (bf16_t)v.w};
    ((bf16x4*)xb)[i] = o;
  }
}

// W[h][d][e] fp32  ->  Wt[hz][e][d] bf16, e padded to EP_ with zeros (4 heads)
__global__ __launch_bounds__(256)
void conv_wkqv(const float* __restrict__ W, bf16_t* __restrict__ Wt, int h0) {
  const int et = blockIdx.x, dt = blockIdx.y, hz = blockIdx.z;
  const int h = h0 + hz;
  const int tx = threadIdx.x & 31, ty = threadIdx.x >> 5;
  __shared__ float tile[32][33];
  const float* Wh = W + (size_t)h * D_ * E_;
  #pragma unroll
  for (int rr = 0; rr < 4; ++rr) {
    int d = dt * 32 + rr * 8 + ty;
    int e = et * 32 + tx;
    tile[rr * 8 + ty][tx] = (e < E_) ? Wh[(size_t)d * E_ + e] : 0.f;
  }
  __syncthreads();
  bf16_t* Wto = Wt + (size_t)hz * EP_ * D_;
  #pragma unroll
  for (int rr = 0; rr < 4; ++rr) {
    int e = et * 32 + rr * 8 + ty;
    int d = dt * 32 + tx;
    Wto[(size_t)e * D_ + d] = (bf16_t)tile[tx][rr * 8 + ty];
  }
}

// Wp[k][n] fp32 -> Wpt[n][k] bf16
__global__ __launch_bounds__(256)
void conv_wp(const float* __restrict__ Wp, bf16_t* __restrict__ Wpt) {
  const int nt = blockIdx.x, kt = blockIdx.y;
  const int tx = threadIdx.x & 31, ty = threadIdx.x >> 5;
  __shared__ float tile[32][33];
  #pragma unroll
  for (int rr = 0; rr < 4; ++rr)
    tile[rr * 8 + ty][tx] = Wp[(size_t)(kt * 32 + rr * 8 + ty) * D_ + nt * 32 + tx];
  __syncthreads();
  #pragma unroll
  for (int rr = 0; rr < 4; ++rr)
    Wpt[(size_t)(nt * 32 + rr * 8 + ty) * D_ + kt * 32 + tx] = (bf16_t)tile[tx][rr * 8 + ty];
}

// ---------------------------------------------------------------------------
// Phase 1: y = x @ Wkqv[h] + b for 4 heads (hz = blockIdx.z), m97 structure.
// K -> Kc[bhl][n][d], Q -> Qc[bhl][n][d] (bhl = b*4+hz, chunk-local),
// V -> Vt[bh][dh][n] (global bh, transposed)
// ---------------------------------------------------------------------------
__global__ __launch_bounds__(256)
void kqv_gemm(const bf16_t* __restrict__ A, const bf16_t* __restrict__ Wt,
              const float* __restrict__ bkqv, int h0,
              bf16_t* __restrict__ Kc, bf16_t* __restrict__ Qc,
              bf16_t* __restrict__ Vt) {
  const int mb = blockIdx.x, nb = blockIdx.y, hz = blockIdx.z;
  const int h = h0 + hz;
  const int t = threadIdx.x;
  const int w = t >> 6, l = t & 63, l15 = l & 15, lg = l >> 4;
  const int wr = (w >> 1) * 64, wc = (w & 1) * 64;

  __shared__ bf16_t As[128 * 64];
  __shared__ bf16_t Bs[128 * 64];
  const bf16_t* Bh = Wt + (size_t)hz * EP_ * D_;

  const int srow = w * 32 + (l >> 3);
  const int scol = (l & 7) * 8;
  const bf16_t* ag = A + (size_t)(mb * 128 + srow) * D_ + scol;
  const bf16_t* bg = Bh + (size_t)(nb * 128 + srow) * D_ + scol;
  char* asl = (char*)As + w * 4096;
  char* bsl = (char*)Bs + w * 4096;

  f32x4 acc[4][4] = {};

  for (int kb = 0; kb < 16; ++kb) {
    __syncthreads();
    #pragma unroll
    for (int i = 0; i < 4; ++i) {
      gload_lds16(ag + (size_t)i * 8 * D_ + kb * 64, asl + i * 1024);
      gload_lds16(bg + (size_t)i * 8 * D_ + kb * 64, bsl + i * 1024);
    }
    __syncthreads();
    #pragma unroll
    for (int ks = 0; ks < 2; ++ks) {
      bf16x8 a[4], b[4];
      #pragma unroll
      for (int mi = 0; mi < 4; ++mi)
        a[mi] = *(const bf16x8*)((const char*)As + (wr + mi * 16 + l15) * 128 + ks * 64 + lg * 16);
      #pragma unroll
      for (int ni = 0; ni < 4; ++ni)
        b[ni] = *(const bf16x8*)((const char*)Bs + (wc + ni * 16 + l15) * 128 + ks * 64 + lg * 16);
      #pragma unroll
      for (int mi = 0; mi < 4; ++mi)
        #pragma unroll
        for (int ni = 0; ni < 4; ++ni)
          acc[mi][ni] = __builtin_amdgcn_mfma_f32_16x16x32_bf16(a[mi], b[ni], acc[mi][ni], 0, 0, 0);
    }
  }

  #pragma unroll
  for (int ni = 0; ni < 4; ++ni) {
    int e = nb * 128 + wc + ni * 16 + l15;
    if (e < E_) {
      float bias = bkqv[h * E_ + e];
      #pragma unroll
      for (int mi = 0; mi < 4; ++mi) {
        #pragma unroll
        for (int r = 0; r < 4; ++r) {
          int grow = mb * 128 + wr + mi * 16 + lg * 4 + r;
          bf16_t bv = (bf16_t)(acc[mi][ni][r] + bias);
          int b = grow >> 10, n = grow & (N_ - 1);
          int bhl = b * 4 + hz;
          if (e < D_)
            Kc[((size_t)bhl * N_ + n) * D_ + e] = bv;
          else if (e < 2 * D_)
            Qc[((size_t)bhl * N_ + n) * D_ + (e - D_)] = bv;
          else
            Vt[(((size_t)(b * H_ + h)) * DH_ + (e - 2 * D_)) * N_ + n] = bv;
        }
      }
    }
  }
}

// ---------------------------------------------------------------------------
// Phase 2a: S = scale * Q . K^T, lower-triangle 128x128 tiles only.
// m97 structure; epilogue applies scale (log2e/32) + causal mask, writes f32.
// ---------------------------------------------------------------------------
__global__ __launch_bounds__(256)
void s_gemm(const bf16_t* __restrict__ Qc, const bf16_t* __restrict__ Kc,
            float* __restrict__ Sg) {
  const int idx = blockIdx.x;   // 0..35 lower-triangle tile id
  const int bhl = blockIdx.y;   // 0..15
  int qt = 0;
  while ((qt + 1) * (qt + 2) / 2 <= idx) ++qt;
  const int kt = idx - qt * (qt + 1) / 2;

  const int t = threadIdx.x;
  const int w = t >> 6, l = t & 63, l15 = l & 15, lg = l >> 4;
  const int wr = (w >> 1) * 64, wc = (w & 1) * 64;

  __shared__ bf16_t As[128 * 64];
  __shared__ bf16_t Bs[128 * 64];

  const bf16_t* Ah = Qc + (size_t)bhl * N_ * D_ + (size_t)qt * 128 * D_;
  const bf16_t* Bh = Kc + (size_t)bhl * N_ * D_ + (size_t)kt * 128 * D_;

  const int srow = w * 32 + (l >> 3);
  const int scol = (l & 7) * 8;
  const bf16_t* ag = Ah + (size_t)srow * D_ + scol;
  const bf16_t* bg = Bh + (size_t)srow * D_ + scol;
  char* asl = (char*)As + w * 4096;
  char* bsl = (char*)Bs + w * 4096;

  f32x4 acc[4][4] = {};

  for (int kb = 0; kb < 16; ++kb) {
    __syncthreads();
    #pragma unroll
    for (int i = 0; i < 4; ++i) {
      gload_lds16(ag + (size_t)i * 8 * D_ + kb * 64, asl + i * 1024);
      gload_lds16(bg + (size_t)i * 8 * D_ + kb * 64, bsl + i * 1024);
    }
    __syncthreads();
    #pragma unroll
    for (int ks = 0; ks < 2; ++ks) {
      bf16x8 a[4], b[4];
      #pragma unroll
      for (int mi = 0; mi < 4; ++mi)
        a[mi] = *(const bf16x8*)((const char*)As + (wr + mi * 16 + l15) * 128 + ks * 64 + lg * 16);
      #pragma unroll
      for (int ni = 0; ni < 4; ++ni)
        b[ni] = *(const bf16x8*)((const char*)Bs + (wc + ni * 16 + l15) * 128 + ks * 64 + lg * 16);
      #pragma unroll
      for (int mi = 0; mi < 4; ++mi)
        #pragma unroll
        for (int ni = 0; ni < 4; ++ni)
          acc[mi][ni] = __builtin_amdgcn_mfma_f32_16x16x32_bf16(a[mi], b[ni], acc[mi][ni], 0, 0, 0);
    }
  }

  const float SCALE = 0.045084220027780106f;   // log2(e)/sqrt(1024)
  float* So = Sg + ((size_t)bhl << 20);
  #pragma unroll
  for (int ni = 0; ni < 4; ++ni) {
    int gcol = kt * 128 + wc + ni * 16 + l15;
    #pragma unroll
    for (int mi = 0; mi < 4; ++mi)
      #pragma unroll
      for (int r = 0; r < 4; ++r) {
        int grow = qt * 128 + wr + mi * 16 + lg * 4 + r;
        float z = acc[mi][ni][r] * SCALE;
        if (gcol > grow) z = -1e30f;
        So[(size_t)grow * N_ + gcol] = z;
      }
  }
}

// ---------------------------------------------------------------------------
// Phase 2b: softmax + P.V, zero LDS, zero barriers. Wave owns 16 q-rows.
// S read in A-frag layout (row = l&15, k = (l>>4)*8) -> P stays in registers.
// ---------------------------------------------------------------------------
__global__ __launch_bounds__(256)
void softmax_pv(const float* __restrict__ Sg, const bf16_t* __restrict__ Vt,
                bf16_t* __restrict__ sa, int c) {
  const int qt = blockIdx.x;   // 0..15 (64-row tiles)
  const int bhl = blockIdx.y;  // 0..15
  const int t = threadIdx.x;
  const int w = t >> 6, l = t & 63, l15 = l & 15, lg = l >> 4;
  const int b = bhl >> 2, h = c * 4 + (bhl & 3);
  const int bh = b * H_ + h;

  const float* Srow = Sg + ((size_t)bhl << 20) + (size_t)(qt * 64 + w * 16 + l15) * N_;
  const bf16_t* Vh = Vt + (size_t)bh * DH_ * N_;

  f32x4 accO[4] = {};
  float m = -1e30f, lsum = 0.f;

  for (int j = 0; j <= qt; ++j) {
    const int jb = j * 64;
    float4 sA = *(const float4*)(Srow + jb + lg * 8);
    float4 sB = *(const float4*)(Srow + jb + lg * 8 + 4);
    float4 sC = *(const float4*)(Srow + jb + 32 + lg * 8);
    float4 sD = *(const float4*)(Srow + jb + 32 + lg * 8 + 4);

    float zm = fmaxf(fmaxf(fmaxf(sA.x, sA.y), fmaxf(sA.z, sA.w)),
                     fmaxf(fmaxf(sB.x, sB.y), fmaxf(sB.z, sB.w)));
    zm = fmaxf(zm, fmaxf(fmaxf(fmaxf(sC.x, sC.y), fmaxf(sC.z, sC.w)),
                         fmaxf(fmaxf(sD.x, sD.y), fmaxf(sD.z, sD.w))));
    zm = fmaxf(zm, __shfl_xor(zm, 16));
    zm = fmaxf(zm, __shfl_xor(zm, 32));

    float mnew = fmaxf(m, zm);
    float scl = exp2f(m - mnew);
    m = mnew;

    float p[16];
    p[0] = exp2f(sA.x - mnew); p[1] = exp2f(sA.y - mnew);
    p[2] = exp2f(sA.z - mnew); p[3] = exp2f(sA.w - mnew);
    p[4] = exp2f(sB.x - mnew); p[5] = exp2f(sB.y - mnew);
    p[6] = exp2f(sB.z - mnew); p[7] = exp2f(sB.w - mnew);
    p[8] = exp2f(sC.x - mnew); p[9] = exp2f(sC.y - mnew);
    p[10] = exp2f(sC.z - mnew); p[11] = exp2f(sC.w - mnew);
    p[12] = exp2f(sD.x - mnew); p[13] = exp2f(sD.y - mnew);
    p[14] = exp2f(sD.z - mnew); p[15] = exp2f(sD.w - mnew);

    float rs = 0.f;
    #pragma unroll
    for (int i = 0; i < 16; ++i) rs += p[i];
    rs += __shfl_xor(rs, 16);
    rs += __shfl_xor(rs, 32);
    lsum = lsum * scl + rs;

    // transport rescale factor from A-frag row domain (l15) to C-frag rows (lg*4+r)
    float sclO[4];
    #pragma unroll
    for (int r = 0; r < 4; ++r) sclO[r] = __shfl(scl, lg * 4 + r);
    #pragma unroll
    for (int db = 0; db < 4; ++db)
      #pragma unroll
      for (int r = 0; r < 4; ++r) accO[db][r] *= sclO[r];

    bf16x8 pa0 = {(bf16_t)p[0], (bf16_t)p[1], (bf16_t)p[2], (bf16_t)p[3],
                  (bf16_t)p[4], (bf16_t)p[5], (bf16_t)p[6], (bf16_t)p[7]};
    bf16x8 pa1 = {(bf16_t)p[8], (bf16_t)p[9], (bf16_t)p[10], (bf16_t)p[11],
                  (bf16_t)p[12], (bf16_t)p[13], (bf16_t)p[14], (bf16_t)p[15]};

    #pragma unroll
    for (int db = 0; db < 4; ++db) {
      const bf16_t* vp = Vh + (size_t)(db * 16 + l15) * N_ + jb;
      bf16x8 vb0 = *(const bf16x8*)(vp + lg * 8);
      bf16x8 vb1 = *(const bf16x8*)(vp + 32 + lg * 8);
      accO[db] = __builtin_amdgcn_mfma_f32_16x16x32_bf16(pa0, vb0, accO[db], 0, 0, 0);
      accO[db] = __builtin_amdgcn_mfma_f32_16x16x32_bf16(pa1, vb1, accO[db], 0, 0, 0);
    }
  }

  float lO[4];
  #pragma unroll
  for (int r = 0; r < 4; ++r) lO[r] = __shfl(lsum, lg * 4 + r);

  #pragma unroll
  for (int db = 0; db < 4; ++db)
    #pragma unroll
    for (int r = 0; r < 4; ++r) {
      int row = qt * 64 + w * 16 + lg * 4 + r;
      int col = h * DH_ + db * 16 + l15;
      sa[((size_t)b * N_ + row) * D_ + col] = (bf16_t)(accO[db][r] / lO[r]);
    }
}

// ---------------------------------------------------------------------------
// Phase 3: out = sa @ Wp + bp   (m97 structure, fp32 out)
// ---------------------------------------------------------------------------
__global__ __launch_bounds__(256)
void out_gemm(const bf16_t* __restrict__ A, const bf16_t* __restrict__ Bt,
              const float* __restrict__ bp, float* __restrict__ out) {
  const int mb = blockIdx.x, nb = blockIdx.y;
  const int t = threadIdx.x;
  const int w = t >> 6, l = t & 63, l15 = l & 15, lg = l >> 4;
  const int wr = (w >> 1) * 64, wc = (w & 1) * 64;

  __shared__ bf16_t As[128 * 64];
  __shared__ bf16_t Bs[128 * 64];

  const int srow = w * 32 + (l >> 3);
  const int scol = (l & 7) * 8;
  const bf16_t* ag = A + (size_t)(mb * 128 + srow) * D_ + scol;
  const bf16_t* bg = Bt + (size_t)(nb * 128 + srow) * D_ + scol;
  char* asl = (char*)As + w * 4096;
  char* bsl = (char*)Bs + w * 4096;

  f32x4 acc[4][4] = {};

  for (int kb = 0; kb < 16; ++kb) {
    __syncthreads();
    #pragma unroll
    for (int i = 0; i < 4; ++i) {
      gload_lds16(ag + (size_t)i * 8 * D_ + kb * 64, asl + i * 1024);
      gload_lds16(bg + (size_t)i * 8 * D_ + kb * 64, bsl + i * 1024);
    }
    __syncthreads();
    #pragma unroll
    for (int ks = 0; ks < 2; ++ks) {
      bf16x8 a[4], b[4];
      #pragma unroll
      for (int mi = 0; mi < 4; ++mi)
        a[mi] = *(const bf16x8*)((const char*)As + (wr + mi * 16 + l15) * 128 + ks * 64 + lg * 16);
      #pragma unroll
      for (int ni = 0; ni < 4; ++ni)
        b[ni] = *(const bf16x8*)((const char*)Bs + (wc + ni * 16 + l15) * 128 + ks * 64 + lg * 16);
      #pragma unroll
      for (int mi = 0; mi < 4; ++mi)
        #pragma unroll
        for (int ni = 0; ni < 4; ++ni)
          acc[mi][ni] = __builtin_amdgcn_mfma_f32_16x16x32_bf16(a[mi], b[ni], acc[mi][ni], 0, 0, 0);
    }
  }

  #pragma unroll
  for (int ni = 0; ni < 4; ++ni) {
    int e = nb * 128 + wc + ni * 16 + l15;
    float bias = bp[e];
    #pragma unroll
    for (int mi = 0; mi < 4; ++mi)
      #pragma unroll
      for (int r = 0; r < 4; ++r) {
        int grow = mb * 128 + wr + mi * 16 + lg * 4 + r;
        out[(size_t)grow * D_ + e] = acc[mi][ni][r] + bias;
      }
  }
}

// ---------------------------------------------------------------------------
extern "C" void kernel_launch(void* const* d_in, const int* in_sizes, int n_in,
                              void* d_out, int out_size, void* d_ws, size_t ws_size,
                              hipStream_t stream) {
  const float* x    = (const float*)d_in[0];
  const float* Wkqv = (const float*)d_in[1];
  const float* bkqv = (const float*)d_in[2];
  const float* Wp   = (const float*)d_in[3];
  const float* bp   = (const float*)d_in[4];
  float* out = (float*)d_out;
  char* ws = (char*)d_ws;

  const size_t SZ_XB  = (size_t)ROWS_ * D_ * 2;            //  8 MiB
  const size_t SZ_SA  = (size_t)ROWS_ * D_ * 2;            //  8 MiB
  const size_t SZ_WPT = (size_t)D_ * D_ * 2;               //  2 MiB
  const size_t SZ_VT  = (size_t)B_ * H_ * DH_ * N_ * 2;    //  8 MiB
  const size_t SZ_QC  = (size_t)16 * N_ * D_ * 2;          // 32 MiB (16 bh)
  const size_t SZ_WT  = (size_t)4 * EP_ * D_ * 2;          // 17 MiB (4 heads)
  // Sg: 16 bh x 1024 x 1024 f32 = 64 MiB

  bf16_t* xb  = (bf16_t*)(ws);
  bf16_t* sa  = (bf16_t*)(ws + SZ_XB);
  bf16_t* Wpt = (bf16_t*)(ws + SZ_XB + SZ_SA);
  bf16_t* Vt  = (bf16_t*)(ws + SZ_XB + SZ_SA + SZ_WPT);
  bf16_t* Qc  = (bf16_t*)(ws + SZ_XB + SZ_SA + SZ_WPT + SZ_VT);
  bf16_t* Kc  = (bf16_t*)(ws + SZ_XB + SZ_SA + SZ_WPT + SZ_VT + SZ_QC);
  bf16_t* Wt  = (bf16_t*)(ws + SZ_XB + SZ_SA + SZ_WPT + SZ_VT + 2 * SZ_QC);
  float*  Sg  = (float*) (ws + SZ_XB + SZ_SA + SZ_WPT + SZ_VT + 2 * SZ_QC + SZ_WT);
  // total = 8+8+2+8+32+32+17+64 = 171 MiB  (<< proven-safe 287 MiB)

  hipLaunchKernelGGL(conv_x, dim3(1024), dim3(256), 0, stream, x, xb);
  hipLaunchKernelGGL(conv_wp, dim3(32, 32), dim3(256), 0, stream, Wp, Wpt);

  for (int c = 0; c < 4; ++c) {
    hipLaunchKernelGGL(conv_wkqv, dim3(68, 32, 4), dim3(256), 0, stream,
                       Wkqv, Wt, c * 4);
    hipLaunchKernelGGL(kqv_gemm, dim3(32, 17, 4), dim3(256), 0, stream,
                       xb, Wt, bkqv, c * 4, Kc, Qc, Vt);
    hipLaunchKernelGGL(s_gemm, dim3(36, 16), dim3(256), 0, stream, Qc, Kc, Sg);
    hipLaunchKernelGGL(softmax_pv, dim3(16, 16), dim3(256), 0, stream,
                       Sg, Vt, sa, c);
  }

  hipLaunchKernelGGL(out_gemm, dim3(32, 8), dim3(256), 0, stream, sa, Wpt, bp, out);
}

// Round 4
// 719.118 us; speedup vs baseline: 3.6324x; 1.1537x over previous
//
#include <hip/hip_runtime.h>
#include <hip/hip_bf16.h>

#define B_ 4
#define N_ 1024
#define D_ 1024
#define H_ 16
#define DH_ 64
#define E_ 2112
#define EP2_ 2304
#define ROWS_ 4096

typedef __bf16 bf16_t;
typedef bf16_t bf16x4 __attribute__((ext_vector_type(4)));
typedef bf16_t bf16x8 __attribute__((ext_vector_type(8)));
typedef float f32x4 __attribute__((ext_vector_type(4)));

__device__ __forceinline__ void gload_lds16(const void* g, void* l) {
  __builtin_amdgcn_global_load_lds(
      (const __attribute__((address_space(1))) void*)g,
      (__attribute__((address_space(3))) void*)l, 16, 0, 0);
}

// ---------------------------------------------------------------------------
// conversion passes
// ---------------------------------------------------------------------------
__global__ __launch_bounds__(256)
void conv_x(const float* __restrict__ x, bf16_t* __restrict__ xb) {
  const int n4 = ROWS_ * D_ / 4;
  for (int i = blockIdx.x * 256 + threadIdx.x; i < n4; i += gridDim.x * 256) {
    float4 v = ((const float4*)x)[i];
    bf16x4 o = {(bf16_t)v.x, (bf16_t)v.y, (bf16_t)v.z, (bf16_t)v.w};
    ((bf16x4*)xb)[i] = o;
  }
}

// W[h][d][e] fp32 -> Wt[hz][e][d] bf16, e padded to EP2_ with zeros (8 heads)
__global__ __launch_bounds__(256)
void conv_wkqv(const float* __restrict__ W, bf16_t* __restrict__ Wt, int h0) {
  const int et = blockIdx.x, dt = blockIdx.y, hz = blockIdx.z;
  const int h = h0 + hz;
  const int tx = threadIdx.x & 31, ty = threadIdx.x >> 5;
  __shared__ float tile[32][33];
  const float* Wh = W + (size_t)h * D_ * E_;
  #pragma unroll
  for (int rr = 0; rr < 4; ++rr) {
    int d = dt * 32 + rr * 8 + ty;
    int e = et * 32 + tx;
    tile[rr * 8 + ty][tx] = (e < E_) ? Wh[(size_t)d * E_ + e] : 0.f;
  }
  __syncthreads();
  bf16_t* Wto = Wt + (size_t)hz * EP2_ * D_;
  #pragma unroll
  for (int rr = 0; rr < 4; ++rr) {
    int e = et * 32 + rr * 8 + ty;
    int d = dt * 32 + tx;
    Wto[(size_t)e * D_ + d] = (bf16_t)tile[tx][rr * 8 + ty];
  }
}

// Wp[k][n] fp32 -> Wpt[n][k] bf16
__global__ __launch_bounds__(256)
void conv_wp(const float* __restrict__ Wp, bf16_t* __restrict__ Wpt) {
  const int nt = blockIdx.x, kt = blockIdx.y;
  const int tx = threadIdx.x & 31, ty = threadIdx.x >> 5;
  __shared__ float tile[32][33];
  #pragma unroll
  for (int rr = 0; rr < 4; ++rr)
    tile[rr * 8 + ty][tx] = Wp[(size_t)(kt * 32 + rr * 8 + ty) * D_ + nt * 32 + tx];
  __syncthreads();
  #pragma unroll
  for (int rr = 0; rr < 4; ++rr)
    Wpt[(size_t)(nt * 32 + rr * 8 + ty) * D_ + kt * 32 + tx] = (bf16_t)tile[tx][rr * 8 + ty];
}

// ---------------------------------------------------------------------------
// 256x256xK=1024 phase-split MFMA core. 512 threads = 8 waves (2M x 4N).
// BK=64, 2 LDS dbufs, 4 phases/K-tile. LDS reads XOR-swizzled (T2), inverse
// swizzle pre-applied to the per-lane global source (linear gload_lds dest).
// Prefetch: tile kt+1 staged during tile kt's phases into buf[(kt+1)&1]
// (that buffer's old content, tile kt-1, was fully read before tile kt began
// -> race-free). Single vmcnt drain per tile at ph3 with >=1 phase of cover.
// A/B strides fixed at 1024 elements.
// ---------------------------------------------------------------------------
__device__ __forceinline__ void mm256_core(const bf16_t* __restrict__ Ag,
                                           const bf16_t* __restrict__ Bg,
                                           f32x4 (&acc)[8][4]) {
  __shared__ bf16_t As[2][16384];
  __shared__ bf16_t Bs[2][16384];
  const int t = threadIdx.x;
  const int w = t >> 6, l = t & 63, l15 = l & 15, lg = l >> 4;
  const int wm = w >> 2, wn = w & 3;

  // staging: row within half = w*8 + (l>>3) (+64 per second instr, +128*h)
  // source col pre-swizzled: chunk = (l&7) ^ (l>>3)  (16B units)
  const int srow = w * 8 + (l >> 3);
  const int scol = (((l & 7) ^ (l >> 3)) << 3);
  const bf16_t* aS = Ag + (size_t)srow * 1024 + scol;
  const bf16_t* bS = Bg + (size_t)srow * 1024 + scol;

#define STG_(SRC, LDS, bufi, kt, h)                                          \
  do {                                                                       \
    gload_lds16(SRC + (size_t)((h) * 128) * 1024 + (kt) * 64,                \
                (char*)LDS[bufi] + (h) * 16384 + w * 1024);                  \
    gload_lds16(SRC + (size_t)((h) * 128 + 64) * 1024 + (kt) * 64,           \
                (char*)LDS[bufi] + (h) * 16384 + 8192 + w * 1024);           \
  } while (0)

  // prologue: stage tile 0 into buf0
  STG_(bS, Bs, 0, 0, 0);
  STG_(bS, Bs, 0, 0, 1);
  STG_(aS, As, 0, 0, 0);
  STG_(aS, As, 0, 0, 1);
  asm volatile("s_waitcnt vmcnt(0)" ::: "memory");
  __builtin_amdgcn_s_barrier();

  const int rswz = (l15 & 7) << 4;

  for (int kt = 0; kt < 16; ++kt) {
    const char* Ab = (const char*)As[kt & 1] + wm * 16384;
    const char* Bb = (const char*)Bs[kt & 1] + (wn >> 1) * 16384;
    const int nkt = kt + 1;
    bf16x8 b[4];
    #pragma unroll
    for (int ph = 0; ph < 4; ++ph) {
      const int ks = ph >> 1, mh = ph & 1;
      const int cswz = (ks * 64 + lg * 16) ^ rswz;
      if (mh == 0) {
        #pragma unroll
        for (int ni = 0; ni < 4; ++ni)
          b[ni] = *(const bf16x8*)(Bb + ((wn & 1) * 64 + ni * 16 + l15) * 128 + cswz);
      }
      bf16x8 a[4];
      #pragma unroll
      for (int mi = 0; mi < 4; ++mi)
        a[mi] = *(const bf16x8*)(Ab + (mh * 64 + mi * 16 + l15) * 128 + cswz);
      if (nkt < 16) {
        if (ph == 0) STG_(bS, Bs, nkt & 1, nkt, 0);
        if (ph == 1) STG_(bS, Bs, nkt & 1, nkt, 1);
        if (ph == 2) STG_(aS, As, nkt & 1, nkt, 0);
        if (ph == 3) STG_(aS, As, nkt & 1, nkt, 1);
      }
      __builtin_amdgcn_s_barrier();
      asm volatile("s_waitcnt lgkmcnt(0)" ::: "memory");
      __builtin_amdgcn_s_setprio(1);
      #pragma unroll
      for (int mi = 0; mi < 4; ++mi)
        #pragma unroll
        for (int ni = 0; ni < 4; ++ni)
          acc[mh * 4 + mi][ni] = __builtin_amdgcn_mfma_f32_16x16x32_bf16(
              a[mi], b[ni], acc[mh * 4 + mi][ni], 0, 0, 0);
      __builtin_amdgcn_s_setprio(0);
      if (ph == 3) asm volatile("s_waitcnt vmcnt(0)" ::: "memory");
      __builtin_amdgcn_s_barrier();
    }
  }
#undef STG_
}

// ---------------------------------------------------------------------------
// Phase 1: y = x @ Wkqv[h] + b for 8 heads. 256^2 core.
// K -> Kc[bhl][n][d], Q -> Qc[bhl][n][d] (bhl = b*8+hz), V -> Vt[bh][dh][n]
// ---------------------------------------------------------------------------
__global__ __launch_bounds__(512)
void kqv256(const bf16_t* __restrict__ xb, const bf16_t* __restrict__ Wt,
            const float* __restrict__ bkqv, int h0,
            bf16_t* __restrict__ Kc, bf16_t* __restrict__ Qc,
            bf16_t* __restrict__ Vt) {
  const int mb = blockIdx.x, nb = blockIdx.y, hz = blockIdx.z;
  f32x4 acc[8][4] = {};
  mm256_core(xb + (size_t)mb * 256 * D_,
             Wt + ((size_t)hz * EP2_ + (size_t)nb * 256) * D_, acc);

  const int t = threadIdx.x;
  const int w = t >> 6, l = t & 63, l15 = l & 15, lg = l >> 4;
  const int wm = w >> 2, wn = w & 3;
  const int h = h0 + hz;

  #pragma unroll
  for (int ni = 0; ni < 4; ++ni) {
    int e = nb * 256 + wn * 64 + ni * 16 + l15;
    if (e < E_) {
      float bias = bkqv[h * E_ + e];
      #pragma unroll
      for (int mi = 0; mi < 8; ++mi) {
        #pragma unroll
        for (int r = 0; r < 4; ++r) {
          int grow = mb * 256 + wm * 128 + mi * 16 + lg * 4 + r;
          bf16_t bv = (bf16_t)(acc[mi][ni][r] + bias);
          int b = grow >> 10, n = grow & (N_ - 1);
          int bhl = b * 8 + hz;
          if (e < D_)
            Kc[((size_t)bhl * N_ + n) * D_ + e] = bv;
          else if (e < 2 * D_)
            Qc[((size_t)bhl * N_ + n) * D_ + (e - D_)] = bv;
          else
            Vt[(((size_t)(b * H_ + h)) * DH_ + (e - 2 * D_)) * N_ + n] = bv;
        }
      }
    }
  }
}

// ---------------------------------------------------------------------------
// Phase 2a: S = scale * Q.K^T, lower-triangle 256x256 tiles (10 per bh).
// Compact storage: tile id = qt*(qt+1)/2+kt, 256KB per tile, f32.
// ---------------------------------------------------------------------------
__global__ __launch_bounds__(512)
void s_gemm256(const bf16_t* __restrict__ Qc, const bf16_t* __restrict__ Kc,
               float* __restrict__ SgC) {
  const int idx = blockIdx.x;   // 0..9
  const int bhl = blockIdx.y;   // 0..31
  int qt = 0;
  while ((qt + 1) * (qt + 2) / 2 <= idx) ++qt;
  const int kt = idx - qt * (qt + 1) / 2;

  f32x4 acc[8][4] = {};
  mm256_core(Qc + ((size_t)bhl * N_ + (size_t)qt * 256) * D_,
             Kc + ((size_t)bhl * N_ + (size_t)kt * 256) * D_, acc);

  const int t = threadIdx.x;
  const int w = t >> 6, l = t & 63, l15 = l & 15, lg = l >> 4;
  const int wm = w >> 2, wn = w & 3;
  const float SCALE = 0.045084220027780106f;   // log2(e)/sqrt(1024)
  float* So = SgC + (((size_t)bhl * 10 + idx) << 16);

  #pragma unroll
  for (int ni = 0; ni < 4; ++ni) {
    int cl = wn * 64 + ni * 16 + l15;
    #pragma unroll
    for (int mi = 0; mi < 8; ++mi)
      #pragma unroll
      for (int r = 0; r < 4; ++r) {
        int rl = wm * 128 + mi * 16 + lg * 4 + r;
        float z = acc[mi][ni][r] * SCALE;
        if (kt * 256 + cl > qt * 256 + rl) z = -1e30f;
        So[(size_t)rl * 256 + cl] = z;
      }
  }
}

// ---------------------------------------------------------------------------
// Phase 2b: softmax + P.V, zero LDS/barriers. Wave owns 16 q-rows.
// S read from compact triangle tiles in A-frag layout; P stays in registers.
// ---------------------------------------------------------------------------
__global__ __launch_bounds__(256)
void softmax_pv(const float* __restrict__ SgC, const bf16_t* __restrict__ Vt,
                bf16_t* __restrict__ sa, int c) {
  const int qt = blockIdx.x;   // 0..15 (64-row q tiles)
  const int bhl = blockIdx.y;  // 0..31
  const int t = threadIdx.x;
  const int w = t >> 6, l = t & 63, l15 = l & 15, lg = l >> 4;
  const int b = bhl >> 3, h = c * 8 + (bhl & 7);
  const int bh = b * H_ + h;

  const int qrow = qt * 64 + w * 16 + l15;
  const int qt8 = qt >> 2;
  const float* Sbh = SgC + (((size_t)bhl * 10) << 16);
  const bf16_t* Vh = Vt + (size_t)bh * DH_ * N_;

  f32x4 accO[4] = {};
  float m = -1e30f, lsum = 0.f;

  for (int j = 0; j <= qt; ++j) {
    const int jb = j * 64;
    const int tid = qt8 * (qt8 + 1) / 2 + (j >> 2);
    const float* Srow = Sbh + ((size_t)tid << 16) + (size_t)(qrow & 255) * 256 + (jb & 255);

    float4 sA = *(const float4*)(Srow + lg * 8);
    float4 sB = *(const float4*)(Srow + lg * 8 + 4);
    float4 sC = *(const float4*)(Srow + 32 + lg * 8);
    float4 sD = *(const float4*)(Srow + 32 + lg * 8 + 4);

    float zm = fmaxf(fmaxf(fmaxf(sA.x, sA.y), fmaxf(sA.z, sA.w)),
                     fmaxf(fmaxf(sB.x, sB.y), fmaxf(sB.z, sB.w)));
    zm = fmaxf(zm, fmaxf(fmaxf(fmaxf(sC.x, sC.y), fmaxf(sC.z, sC.w)),
                         fmaxf(fmaxf(sD.x, sD.y), fmaxf(sD.z, sD.w))));
    zm = fmaxf(zm, __shfl_xor(zm, 16));
    zm = fmaxf(zm, __shfl_xor(zm, 32));

    float mnew = fmaxf(m, zm);
    float scl = exp2f(m - mnew);
    m = mnew;

    float p[16];
    p[0] = exp2f(sA.x - mnew); p[1] = exp2f(sA.y - mnew);
    p[2] = exp2f(sA.z - mnew); p[3] = exp2f(sA.w - mnew);
    p[4] = exp2f(sB.x - mnew); p[5] = exp2f(sB.y - mnew);
    p[6] = exp2f(sB.z - mnew); p[7] = exp2f(sB.w - mnew);
    p[8] = exp2f(sC.x - mnew); p[9] = exp2f(sC.y - mnew);
    p[10] = exp2f(sC.z - mnew); p[11] = exp2f(sC.w - mnew);
    p[12] = exp2f(sD.x - mnew); p[13] = exp2f(sD.y - mnew);
    p[14] = exp2f(sD.z - mnew); p[15] = exp2f(sD.w - mnew);

    float rs = 0.f;
    #pragma unroll
    for (int i = 0; i < 16; ++i) rs += p[i];
    rs += __shfl_xor(rs, 16);
    rs += __shfl_xor(rs, 32);
    lsum = lsum * scl + rs;

    float sclO[4];
    #pragma unroll
    for (int r = 0; r < 4; ++r) sclO[r] = __shfl(scl, lg * 4 + r);
    #pragma unroll
    for (int db = 0; db < 4; ++db)
      #pragma unroll
      for (int r = 0; r < 4; ++r) accO[db][r] *= sclO[r];

    bf16x8 pa0 = {(bf16_t)p[0], (bf16_t)p[1], (bf16_t)p[2], (bf16_t)p[3],
                  (bf16_t)p[4], (bf16_t)p[5], (bf16_t)p[6], (bf16_t)p[7]};
    bf16x8 pa1 = {(bf16_t)p[8], (bf16_t)p[9], (bf16_t)p[10], (bf16_t)p[11],
                  (bf16_t)p[12], (bf16_t)p[13], (bf16_t)p[14], (bf16_t)p[15]};

    #pragma unroll
    for (int db = 0; db < 4; ++db) {
      const bf16_t* vp = Vh + (size_t)(db * 16 + l15) * N_ + jb;
      bf16x8 vb0 = *(const bf16x8*)(vp + lg * 8);
      bf16x8 vb1 = *(const bf16x8*)(vp + 32 + lg * 8);
      accO[db] = __builtin_amdgcn_mfma_f32_16x16x32_bf16(pa0, vb0, accO[db], 0, 0, 0);
      accO[db] = __builtin_amdgcn_mfma_f32_16x16x32_bf16(pa1, vb1, accO[db], 0, 0, 0);
    }
  }

  float lO[4];
  #pragma unroll
  for (int r = 0; r < 4; ++r) lO[r] = __shfl(lsum, lg * 4 + r);

  #pragma unroll
  for (int db = 0; db < 4; ++db)
    #pragma unroll
    for (int r = 0; r < 4; ++r) {
      int row = qt * 64 + w * 16 + lg * 4 + r;
      int col = h * DH_ + db * 16 + l15;
      sa[((size_t)b * N_ + row) * D_ + col] = (bf16_t)(accO[db][r] / lO[r]);
    }
}

// ---------------------------------------------------------------------------
// Phase 3: out = sa @ Wp + bp   (m97 128^2 structure, fp32 out)
// ---------------------------------------------------------------------------
__global__ __launch_bounds__(256)
void out_gemm(const bf16_t* __restrict__ A, const bf16_t* __restrict__ Bt,
              const float* __restrict__ bp, float* __restrict__ out) {
  const int mb = blockIdx.x, nb = blockIdx.y;
  const int t = threadIdx.x;
  const int w = t >> 6, l = t & 63, l15 = l & 15, lg = l >> 4;
  const int wr = (w >> 1) * 64, wc = (w & 1) * 64;

  __shared__ bf16_t As[128 * 64];
  __shared__ bf16_t Bs[128 * 64];

  const int srow = w * 32 + (l >> 3);
  const int scol = (l & 7) * 8;
  const bf16_t* ag = A + (size_t)(mb * 128 + srow) * D_ + scol;
  const bf16_t* bg = Bt + (size_t)(nb * 128 + srow) * D_ + scol;
  char* asl = (char*)As + w * 4096;
  char* bsl = (char*)Bs + w * 4096;

  f32x4 acc[4][4] = {};

  for (int kb = 0; kb < 16; ++kb) {
    __syncthreads();
    #pragma unroll
    for (int i = 0; i < 4; ++i) {
      gload_lds16(ag + (size_t)i * 8 * D_ + kb * 64, asl + i * 1024);
      gload_lds16(bg + (size_t)i * 8 * D_ + kb * 64, bsl + i * 1024);
    }
    __syncthreads();
    #pragma unroll
    for (int ks = 0; ks < 2; ++ks) {
      bf16x8 a[4], b[4];
      #pragma unroll
      for (int mi = 0; mi < 4; ++mi)
        a[mi] = *(const bf16x8*)((const char*)As + (wr + mi * 16 + l15) * 128 + ks * 64 + lg * 16);
      #pragma unroll
      for (int ni = 0; ni < 4; ++ni)
        b[ni] = *(const bf16x8*)((const char*)Bs + (wc + ni * 16 + l15) * 128 + ks * 64 + lg * 16);
      #pragma unroll
      for (int mi = 0; mi < 4; ++mi)
        #pragma unroll
        for (int ni = 0; ni < 4; ++ni)
          acc[mi][ni] = __builtin_amdgcn_mfma_f32_16x16x32_bf16(a[mi], b[ni], acc[mi][ni], 0, 0, 0);
    }
  }

  #pragma unroll
  for (int ni = 0; ni < 4; ++ni) {
    int e = nb * 128 + wc + ni * 16 + l15;
    float bias = bp[e];
    #pragma unroll
    for (int mi = 0; mi < 4; ++mi)
      #pragma unroll
      for (int r = 0; r < 4; ++r) {
        int grow = mb * 128 + wr + mi * 16 + lg * 4 + r;
        out[(size_t)grow * D_ + e] = acc[mi][ni][r] + bias;
      }
  }
}

// ---------------------------------------------------------------------------
extern "C" void kernel_launch(void* const* d_in, const int* in_sizes, int n_in,
                              void* d_out, int out_size, void* d_ws, size_t ws_size,
                              hipStream_t stream) {
  const float* x    = (const float*)d_in[0];
  const float* Wkqv = (const float*)d_in[1];
  const float* bkqv = (const float*)d_in[2];
  const float* Wp   = (const float*)d_in[3];
  const float* bp   = (const float*)d_in[4];
  float* out = (float*)d_out;
  char* ws = (char*)d_ws;

  const size_t SZ_XB  = (size_t)ROWS_ * D_ * 2;            //  8 MiB
  const size_t SZ_SA  = (size_t)ROWS_ * D_ * 2;            //  8 MiB
  const size_t SZ_WPT = (size_t)D_ * D_ * 2;               //  2 MiB
  const size_t SZ_VT  = (size_t)B_ * H_ * DH_ * N_ * 2;    //  8 MiB
  const size_t SZ_QC  = (size_t)32 * N_ * D_ * 2;          // 64 MiB (32 bh)
  const size_t SZ_WT  = (size_t)8 * EP2_ * D_ * 2;         // 36 MiB (8 heads)
  // SgC: 32 bh x 10 tiles x 65536 f32 = 80 MiB

  bf16_t* xb  = (bf16_t*)(ws);
  bf16_t* sa  = (bf16_t*)(ws + SZ_XB);
  bf16_t* Wpt = (bf16_t*)(ws + SZ_XB + SZ_SA);
  bf16_t* Vt  = (bf16_t*)(ws + SZ_XB + SZ_SA + SZ_WPT);
  bf16_t* Qc  = (bf16_t*)(ws + SZ_XB + SZ_SA + SZ_WPT + SZ_VT);
  bf16_t* Kc  = (bf16_t*)(ws + SZ_XB + SZ_SA + SZ_WPT + SZ_VT + SZ_QC);
  bf16_t* Wt  = (bf16_t*)(ws + SZ_XB + SZ_SA + SZ_WPT + SZ_VT + 2 * SZ_QC);
  float*  SgC = (float*) (ws + SZ_XB + SZ_SA + SZ_WPT + SZ_VT + 2 * SZ_QC + SZ_WT);
  // total = 8+8+2+8+64+64+36+80 = 270 MiB = 283,115,520 B (< proven 285 MB)

  hipLaunchKernelGGL(conv_x, dim3(1024), dim3(256), 0, stream, x, xb);
  hipLaunchKernelGGL(conv_wp, dim3(32, 32), dim3(256), 0, stream, Wp, Wpt);

  for (int c = 0; c < 2; ++c) {
    hipLaunchKernelGGL(conv_wkqv, dim3(72, 32, 8), dim3(256), 0, stream,
                       Wkqv, Wt, c * 8);
    hipLaunchKernelGGL(kqv256, dim3(16, 9, 8), dim3(512), 0, stream,
                       xb, Wt, bkqv, c * 8, Kc, Qc, Vt);
    hipLaunchKernelGGL(s_gemm256, dim3(10, 32), dim3(512), 0, stream,
                       Qc, Kc, SgC);
    hipLaunchKernelGGL(softmax_pv, dim3(16, 32), dim3(256), 0, stream,
                       SgC, Vt, sa, c);
  }

  hipLaunchKernelGGL(out_gemm, dim3(32, 8), dim3(256), 0, stream, sa, Wpt, bp, out);
}

// Round 5
// 665.613 us; speedup vs baseline: 3.9244x; 1.0804x over previous
//
#include <hip/hip_runtime.h>
#include <hip/hip_bf16.h>

#define B_ 4
#define N_ 1024
#define D_ 1024
#define H_ 16
#define DH_ 64
#define E_ 2112
#define ROWS_ 4096

typedef __bf16 bf16_t;
typedef bf16_t bf16x4 __attribute__((ext_vector_type(4)));
typedef bf16_t bf16x8 __attribute__((ext_vector_type(8)));
typedef float f32x4 __attribute__((ext_vector_type(4)));

__device__ __forceinline__ void gload_lds16(const void* g, void* l) {
  __builtin_amdgcn_global_load_lds(
      (const __attribute__((address_space(1))) void*)g,
      (__attribute__((address_space(3))) void*)l, 16, 0, 0);
}

// ---------------------------------------------------------------------------
// conversion passes
// ---------------------------------------------------------------------------
__global__ __launch_bounds__(256)
void conv_x(const float* __restrict__ x, bf16_t* __restrict__ xb) {
  const int n4 = ROWS_ * D_ / 4;
  for (int i = blockIdx.x * 256 + threadIdx.x; i < n4; i += gridDim.x * 256) {
    float4 v = ((const float4*)x)[i];
    bf16x4 o = {(bf16_t)v.x, (bf16_t)v.y, (bf16_t)v.z, (bf16_t)v.w};
    ((bf16x4*)xb)[i] = o;
  }
}

// W[h][d][e] fp32 -> Wt[hz][e][d] bf16 for e in [0,2048) (K,Q cols), 8 heads
__global__ __launch_bounds__(256)
void conv_wkqv(const float* __restrict__ W, bf16_t* __restrict__ Wt, int h0) {
  const int et = blockIdx.x, dt = blockIdx.y, hz = blockIdx.z;
  const int h = h0 + hz;
  const int tx = threadIdx.x & 31, ty = threadIdx.x >> 5;
  __shared__ float tile[32][33];
  const float* Wh = W + (size_t)h * D_ * E_;
  #pragma unroll
  for (int rr = 0; rr < 4; ++rr) {
    int d = dt * 32 + rr * 8 + ty;
    int e = et * 32 + tx;
    tile[rr * 8 + ty][tx] = Wh[(size_t)d * E_ + e];
  }
  __syncthreads();
  bf16_t* Wto = Wt + (size_t)hz * 2048 * D_;
  #pragma unroll
  for (int rr = 0; rr < 4; ++rr) {
    int e = et * 32 + rr * 8 + ty;
    int d = dt * 32 + tx;
    Wto[(size_t)e * D_ + d] = (bf16_t)tile[tx][rr * 8 + ty];
  }
}

// W[h][d][2048+dh] fp32 -> Wvt[h][dh][d] bf16 (all 16 heads)
__global__ __launch_bounds__(256)
void conv_wv(const float* __restrict__ W, bf16_t* __restrict__ Wvt) {
  const int et = blockIdx.x, dt = blockIdx.y, h = blockIdx.z;
  const int tx = threadIdx.x & 31, ty = threadIdx.x >> 5;
  __shared__ float tile[32][33];
  const float* Wh = W + (size_t)h * D_ * E_;
  #pragma unroll
  for (int rr = 0; rr < 4; ++rr) {
    int d = dt * 32 + rr * 8 + ty;
    int dh = et * 32 + tx;
    tile[rr * 8 + ty][tx] = Wh[(size_t)d * E_ + 2048 + dh];
  }
  __syncthreads();
  bf16_t* Wvo = Wvt + (size_t)h * DH_ * D_;
  #pragma unroll
  for (int rr = 0; rr < 4; ++rr) {
    int dh = et * 32 + rr * 8 + ty;
    int d = dt * 32 + tx;
    Wvo[(size_t)dh * D_ + d] = (bf16_t)tile[tx][rr * 8 + ty];
  }
}

// Wp[k][n] fp32 -> Wpt[n][k] bf16
__global__ __launch_bounds__(256)
void conv_wp(const float* __restrict__ Wp, bf16_t* __restrict__ Wpt) {
  const int nt = blockIdx.x, kt = blockIdx.y;
  const int tx = threadIdx.x & 31, ty = threadIdx.x >> 5;
  __shared__ float tile[32][33];
  #pragma unroll
  for (int rr = 0; rr < 4; ++rr)
    tile[rr * 8 + ty][tx] = Wp[(size_t)(kt * 32 + rr * 8 + ty) * D_ + nt * 32 + tx];
  __syncthreads();
  #pragma unroll
  for (int rr = 0; rr < 4; ++rr)
    Wpt[(size_t)(nt * 32 + rr * 8 + ty) * D_ + kt * 32 + tx] = (bf16_t)tile[tx][rr * 8 + ty];
}

// ---------------------------------------------------------------------------
// 256x256xK=1024 phase-split MFMA core. 512 threads = 8 waves (2M x 4N).
// BK=64, 2 LDS dbufs, 4 phases/K-tile, XOR-swizzled LDS reads (T2) with the
// inverse swizzle pre-applied to the per-lane global source (linear dest).
// All 8 prefetch loads for tile kt+1 issued at ph0 of tile kt -> the single
// vmcnt(0) drain at ph3 has ~3 phases of MFMA cover. lds = 128KB scratch.
// ---------------------------------------------------------------------------
__device__ __forceinline__ void mm256_core(const bf16_t* __restrict__ Ag,
                                           const bf16_t* __restrict__ Bg,
                                           bf16_t* lds, f32x4 (&acc)[8][4]) {
  bf16_t* Asp = lds;           // [2][16384]
  bf16_t* Bsp = lds + 32768;   // [2][16384]
  const int t = threadIdx.x;
  const int w = t >> 6, l = t & 63, l15 = l & 15, lg = l >> 4;
  const int wm = w >> 2, wn = w & 3;

  const int srow = w * 8 + (l >> 3);
  const int scol = (((l & 7) ^ (l >> 3)) << 3);
  const bf16_t* aS = Ag + (size_t)srow * 1024 + scol;
  const bf16_t* bS = Bg + (size_t)srow * 1024 + scol;

#define STG2_(SRC, BASE, bufi, kt, hh)                                         \
  do {                                                                         \
    gload_lds16((SRC) + (size_t)((hh) * 128) * 1024 + (kt) * 64,               \
                (char*)(BASE) + (bufi) * 32768 + (hh) * 16384 + w * 1024);     \
    gload_lds16((SRC) + (size_t)((hh) * 128 + 64) * 1024 + (kt) * 64,          \
                (char*)(BASE) + (bufi) * 32768 + (hh) * 16384 + 8192 + w * 1024); \
  } while (0)

  STG2_(bS, Bsp, 0, 0, 0);
  STG2_(bS, Bsp, 0, 0, 1);
  STG2_(aS, Asp, 0, 0, 0);
  STG2_(aS, Asp, 0, 0, 1);
  asm volatile("s_waitcnt vmcnt(0)" ::: "memory");
  __builtin_amdgcn_s_barrier();

  const int rswz = (l15 & 7) << 4;

  for (int kt = 0; kt < 16; ++kt) {
    const char* Ab = (const char*)Asp + (kt & 1) * 32768 + wm * 16384;
    const char* Bb = (const char*)Bsp + (kt & 1) * 32768 + (wn >> 1) * 16384;
    const int nkt = kt + 1;
    bf16x8 b[4];
    #pragma unroll
    for (int ph = 0; ph < 4; ++ph) {
      const int ks = ph >> 1, mh = ph & 1;
      const int cswz = (ks * 64 + lg * 16) ^ rswz;
      if (mh == 0) {
        #pragma unroll
        for (int ni = 0; ni < 4; ++ni)
          b[ni] = *(const bf16x8*)(Bb + ((wn & 1) * 64 + ni * 16 + l15) * 128 + cswz);
      }
      bf16x8 a[4];
      #pragma unroll
      for (int mi = 0; mi < 4; ++mi)
        a[mi] = *(const bf16x8*)(Ab + (mh * 64 + mi * 16 + l15) * 128 + cswz);
      if (nkt < 16 && ph == 0) {
        STG2_(bS, Bsp, nkt & 1, nkt, 0);
        STG2_(bS, Bsp, nkt & 1, nkt, 1);
        STG2_(aS, Asp, nkt & 1, nkt, 0);
        STG2_(aS, Asp, nkt & 1, nkt, 1);
      }
      __builtin_amdgcn_s_barrier();
      asm volatile("s_waitcnt lgkmcnt(0)" ::: "memory");
      __builtin_amdgcn_s_setprio(1);
      #pragma unroll
      for (int mi = 0; mi < 4; ++mi)
        #pragma unroll
        for (int ni = 0; ni < 4; ++ni)
          acc[mh * 4 + mi][ni] = __builtin_amdgcn_mfma_f32_16x16x32_bf16(
              a[mi], b[ni], acc[mh * 4 + mi][ni], 0, 0, 0);
      __builtin_amdgcn_s_setprio(0);
      if (ph == 3) asm volatile("s_waitcnt vmcnt(0)" ::: "memory");
      __builtin_amdgcn_s_barrier();
    }
  }
#undef STG2_
}

// ---------------------------------------------------------------------------
// Phase 1: [K|Q] = x @ Wkqv[h][:, :2048] + b for 8 heads. 256^2 core.
// Epilogue: bias in-reg, then LDS transpose -> coalesced 16B bf16x8 stores.
// ---------------------------------------------------------------------------
__global__ __launch_bounds__(512)
void kqv256(const bf16_t* __restrict__ xb, const bf16_t* __restrict__ Wt,
            const float* __restrict__ bkqv, int h0,
            bf16_t* __restrict__ Kc, bf16_t* __restrict__ Qc) {
  __shared__ bf16_t lds[65536];
  const int mb = blockIdx.x, nb = blockIdx.y, hz = blockIdx.z;
  f32x4 acc[8][4] = {};
  mm256_core(xb + (size_t)mb * 256 * D_,
             Wt + ((size_t)hz * 2048 + (size_t)nb * 256) * D_, lds, acc);

  const int t = threadIdx.x;
  const int w = t >> 6, l = t & 63, l15 = l & 15, lg = l >> 4;
  const int wm = w >> 2, wn = w & 3;
  const int h = h0 + hz;

  float bias[4];
  #pragma unroll
  for (int ni = 0; ni < 4; ++ni)
    bias[ni] = bkqv[h * E_ + nb * 256 + wn * 64 + ni * 16 + l15];
  #pragma unroll
  for (int mi = 0; mi < 8; ++mi)
    #pragma unroll
    for (int ni = 0; ni < 4; ++ni)
      #pragma unroll
      for (int r = 0; r < 4; ++r) acc[mi][ni][r] += bias[ni];

  float* Ct = (float*)lds;   // [64][258]
  #pragma unroll
  for (int s = 0; s < 4; ++s) {
    __syncthreads();
    #pragma unroll
    for (int m2 = 0; m2 < 2; ++m2)
      #pragma unroll
      for (int ni = 0; ni < 4; ++ni)
        #pragma unroll
        for (int r = 0; r < 4; ++r)
          Ct[(wm * 32 + m2 * 16 + lg * 4 + r) * 258 + wn * 64 + ni * 16 + l15] =
              acc[2 * s + m2][ni][r];
    __syncthreads();
    #pragma unroll
    for (int it = 0; it < 4; ++it) {
      int row64 = (t >> 5) + it * 16;
      int wmq = row64 >> 5, m2q = (row64 >> 4) & 1, r16 = row64 & 15;
      int c8 = (t & 31) * 8;
      const float* src = &Ct[row64 * 258 + c8];
      bf16x8 o = {(bf16_t)src[0], (bf16_t)src[1], (bf16_t)src[2], (bf16_t)src[3],
                  (bf16_t)src[4], (bf16_t)src[5], (bf16_t)src[6], (bf16_t)src[7]};
      int grow = mb * 256 + wmq * 128 + (2 * s + m2q) * 16 + r16;
      int b = grow >> 10, n = grow & (N_ - 1);
      int bhl = b * 8 + hz;
      size_t base = ((size_t)bhl * N_ + n) * D_;
      if (nb < 4)
        *(bf16x8*)(Kc + base + nb * 256 + c8) = o;
      else
        *(bf16x8*)(Qc + base + nb * 256 - 1024 + c8) = o;
    }
  }
}

// ---------------------------------------------------------------------------
// Phase 2a: S = scale * Q.K^T, lower-triangle 256x256 tiles (10 per bh).
// Epilogue: scale+mask in-reg, LDS transpose -> coalesced f32 stores.
// ---------------------------------------------------------------------------
__global__ __launch_bounds__(512)
void s_gemm256(const bf16_t* __restrict__ Qc, const bf16_t* __restrict__ Kc,
               float* __restrict__ SgC) {
  __shared__ bf16_t lds[65536];
  const int idx = blockIdx.x;   // 0..9
  const int bhl = blockIdx.y;   // 0..31
  int qt = 0;
  while ((qt + 1) * (qt + 2) / 2 <= idx) ++qt;
  const int kt = idx - qt * (qt + 1) / 2;

  f32x4 acc[8][4] = {};
  mm256_core(Qc + ((size_t)bhl * N_ + (size_t)qt * 256) * D_,
             Kc + ((size_t)bhl * N_ + (size_t)kt * 256) * D_, lds, acc);

  const int t = threadIdx.x;
  const int w = t >> 6, l = t & 63, l15 = l & 15, lg = l >> 4;
  const int wm = w >> 2, wn = w & 3;
  const float SCALE = 0.045084220027780106f;   // log2(e)/sqrt(1024)
  float* So = SgC + (((size_t)bhl * 10 + idx) << 16);

  // scale + causal mask in registers
  #pragma unroll
  for (int mi = 0; mi < 8; ++mi)
    #pragma unroll
    for (int ni = 0; ni < 4; ++ni)
      #pragma unroll
      for (int r = 0; r < 4; ++r) {
        int rl = wm * 128 + mi * 16 + lg * 4 + r;
        int cl = wn * 64 + ni * 16 + l15;
        float z = acc[mi][ni][r] * SCALE;
        if (kt * 256 + cl > qt * 256 + rl) z = -1e30f;
        acc[mi][ni][r] = z;
      }

  float* Ct = (float*)lds;   // [64][258]
  #pragma unroll
  for (int s = 0; s < 4; ++s) {
    __syncthreads();
    #pragma unroll
    for (int m2 = 0; m2 < 2; ++m2)
      #pragma unroll
      for (int ni = 0; ni < 4; ++ni)
        #pragma unroll
        for (int r = 0; r < 4; ++r)
          Ct[(wm * 32 + m2 * 16 + lg * 4 + r) * 258 + wn * 64 + ni * 16 + l15] =
              acc[2 * s + m2][ni][r];
    __syncthreads();
    #pragma unroll
    for (int it = 0; it < 4; ++it) {
      int row64 = (t >> 5) + it * 16;
      int wmq = row64 >> 5, m2q = (row64 >> 4) & 1, r16 = row64 & 15;
      int c8 = (t & 31) * 8;
      const float* src = &Ct[row64 * 258 + c8];
      float4 v0 = {src[0], src[1], src[2], src[3]};
      float4 v1 = {src[4], src[5], src[6], src[7]};
      int rl = wmq * 128 + (2 * s + m2q) * 16 + r16;
      *(float4*)(So + (size_t)rl * 256 + c8) = v0;
      *(float4*)(So + (size_t)rl * 256 + c8 + 4) = v1;
    }
  }
}

// ---------------------------------------------------------------------------
// V gemm: Vt[bh][dh][n] = (Wv^T @ x^T) + bias.  A = Wvt[h] (64 x 1024),
// B = xb rows (n). 256 thr / 4 waves, wave tile 64(dh) x 32(n), BK=64.
// ---------------------------------------------------------------------------
__global__ __launch_bounds__(256)
void v_gemm(const bf16_t* __restrict__ xb, const bf16_t* __restrict__ Wvt,
            const float* __restrict__ bkqv, bf16_t* __restrict__ Vt) {
  const int nt = blockIdx.x;   // 0..31 (128 n rows each)
  const int h = blockIdx.y;    // 0..15
  const int t = threadIdx.x;
  const int w = t >> 6, l = t & 63, l15 = l & 15, lg = l >> 4;

  __shared__ bf16_t As2[64 * 64];
  __shared__ bf16_t Bs2[128 * 64];
  const bf16_t* Wvh = Wvt + (size_t)h * DH_ * D_;
  const bf16_t* Bn = xb + (size_t)nt * 128 * D_;

  f32x4 acc[4][2] = {};
  const int rswz = (l15 & 7) << 4;

  for (int kb = 0; kb < 16; ++kb) {
    __syncthreads();
    #pragma unroll
    for (int i = 0; i < 2; ++i) {
      int idx = t + i * 256;
      int row = idx >> 3, c = idx & 7;
      gload_lds16(Wvh + (size_t)row * D_ + kb * 64 + ((c ^ (row & 7)) << 3),
                  (char*)As2 + idx * 16);
    }
    #pragma unroll
    for (int i = 0; i < 4; ++i) {
      int idx = t + i * 256;
      int row = idx >> 3, c = idx & 7;
      gload_lds16(Bn + (size_t)row * D_ + kb * 64 + ((c ^ (row & 7)) << 3),
                  (char*)Bs2 + idx * 16);
    }
    __syncthreads();
    #pragma unroll
    for (int ks = 0; ks < 2; ++ks) {
      const int cswz = (ks * 64 + lg * 16) ^ rswz;
      bf16x8 a[4], b[2];
      #pragma unroll
      for (int mi = 0; mi < 4; ++mi)
        a[mi] = *(const bf16x8*)((const char*)As2 + (mi * 16 + l15) * 128 + cswz);
      #pragma unroll
      for (int ni = 0; ni < 2; ++ni)
        b[ni] = *(const bf16x8*)((const char*)Bs2 + (w * 32 + ni * 16 + l15) * 128 + cswz);
      #pragma unroll
      for (int mi = 0; mi < 4; ++mi)
        #pragma unroll
        for (int ni = 0; ni < 2; ++ni)
          acc[mi][ni] = __builtin_amdgcn_mfma_f32_16x16x32_bf16(a[mi], b[ni], acc[mi][ni], 0, 0, 0);
    }
  }

  #pragma unroll
  for (int mi = 0; mi < 4; ++mi)
    #pragma unroll
    for (int r = 0; r < 4; ++r) {
      int dh = mi * 16 + lg * 4 + r;
      float bias = bkqv[h * E_ + 2048 + dh];
      #pragma unroll
      for (int ni = 0; ni < 2; ++ni) {
        int nn = nt * 128 + w * 32 + ni * 16 + l15;
        int b = nn >> 10, n = nn & (N_ - 1);
        int bh = b * H_ + h;
        Vt[((size_t)bh * DH_ + dh) * N_ + n] = (bf16_t)(acc[mi][ni][r] + bias);
      }
    }
}

// ---------------------------------------------------------------------------
// Phase 2b: softmax + P.V, zero LDS/barriers. Wave owns 16 q-rows.
// ---------------------------------------------------------------------------
__global__ __launch_bounds__(256)
void softmax_pv(const float* __restrict__ SgC, const bf16_t* __restrict__ Vt,
                bf16_t* __restrict__ sa, int c) {
  const int qt = blockIdx.x;   // 0..15 (64-row q tiles)
  const int bhl = blockIdx.y;  // 0..31
  const int t = threadIdx.x;
  const int w = t >> 6, l = t & 63, l15 = l & 15, lg = l >> 4;
  const int b = bhl >> 3, h = c * 8 + (bhl & 7);
  const int bh = b * H_ + h;

  const int qrow = qt * 64 + w * 16 + l15;
  const int qt8 = qt >> 2;
  const float* Sbh = SgC + (((size_t)bhl * 10) << 16);
  const bf16_t* Vh = Vt + (size_t)bh * DH_ * N_;

  f32x4 accO[4] = {};
  float m = -1e30f, lsum = 0.f;

  for (int j = 0; j <= qt; ++j) {
    const int jb = j * 64;
    const int tid = qt8 * (qt8 + 1) / 2 + (j >> 2);
    const float* Srow = Sbh + ((size_t)tid << 16) + (size_t)(qrow & 255) * 256 + (jb & 255);

    float4 sA = *(const float4*)(Srow + lg * 8);
    float4 sB = *(const float4*)(Srow + lg * 8 + 4);
    float4 sC = *(const float4*)(Srow + 32 + lg * 8);
    float4 sD = *(const float4*)(Srow + 32 + lg * 8 + 4);

    float zm = fmaxf(fmaxf(fmaxf(sA.x, sA.y), fmaxf(sA.z, sA.w)),
                     fmaxf(fmaxf(sB.x, sB.y), fmaxf(sB.z, sB.w)));
    zm = fmaxf(zm, fmaxf(fmaxf(fmaxf(sC.x, sC.y), fmaxf(sC.z, sC.w)),
                         fmaxf(fmaxf(sD.x, sD.y), fmaxf(sD.z, sD.w))));
    zm = fmaxf(zm, __shfl_xor(zm, 16));
    zm = fmaxf(zm, __shfl_xor(zm, 32));

    float mnew = fmaxf(m, zm);
    float scl = exp2f(m - mnew);
    m = mnew;

    float p[16];
    p[0] = exp2f(sA.x - mnew); p[1] = exp2f(sA.y - mnew);
    p[2] = exp2f(sA.z - mnew); p[3] = exp2f(sA.w - mnew);
    p[4] = exp2f(sB.x - mnew); p[5] = exp2f(sB.y - mnew);
    p[6] = exp2f(sB.z - mnew); p[7] = exp2f(sB.w - mnew);
    p[8] = exp2f(sC.x - mnew); p[9] = exp2f(sC.y - mnew);
    p[10] = exp2f(sC.z - mnew); p[11] = exp2f(sC.w - mnew);
    p[12] = exp2f(sD.x - mnew); p[13] = exp2f(sD.y - mnew);
    p[14] = exp2f(sD.z - mnew); p[15] = exp2f(sD.w - mnew);

    float rs = 0.f;
    #pragma unroll
    for (int i = 0; i < 16; ++i) rs += p[i];
    rs += __shfl_xor(rs, 16);
    rs += __shfl_xor(rs, 32);
    lsum = lsum * scl + rs;

    float sclO[4];
    #pragma unroll
    for (int r = 0; r < 4; ++r) sclO[r] = __shfl(scl, lg * 4 + r);
    #pragma unroll
    for (int db = 0; db < 4; ++db)
      #pragma unroll
      for (int r = 0; r < 4; ++r) accO[db][r] *= sclO[r];

    bf16x8 pa0 = {(bf16_t)p[0], (bf16_t)p[1], (bf16_t)p[2], (bf16_t)p[3],
                  (bf16_t)p[4], (bf16_t)p[5], (bf16_t)p[6], (bf16_t)p[7]};
    bf16x8 pa1 = {(bf16_t)p[8], (bf16_t)p[9], (bf16_t)p[10], (bf16_t)p[11],
                  (bf16_t)p[12], (bf16_t)p[13], (bf16_t)p[14], (bf16_t)p[15]};

    #pragma unroll
    for (int db = 0; db < 4; ++db) {
      const bf16_t* vp = Vh + (size_t)(db * 16 + l15) * N_ + jb;
      bf16x8 vb0 = *(const bf16x8*)(vp + lg * 8);
      bf16x8 vb1 = *(const bf16x8*)(vp + 32 + lg * 8);
      accO[db] = __builtin_amdgcn_mfma_f32_16x16x32_bf16(pa0, vb0, accO[db], 0, 0, 0);
      accO[db] = __builtin_amdgcn_mfma_f32_16x16x32_bf16(pa1, vb1, accO[db], 0, 0, 0);
    }
  }

  float lO[4];
  #pragma unroll
  for (int r = 0; r < 4; ++r) lO[r] = __shfl(lsum, lg * 4 + r);

  #pragma unroll
  for (int db = 0; db < 4; ++db)
    #pragma unroll
    for (int r = 0; r < 4; ++r) {
      int row = qt * 64 + w * 16 + lg * 4 + r;
      int col = h * DH_ + db * 16 + l15;
      sa[((size_t)b * N_ + row) * D_ + col] = (bf16_t)(accO[db][r] / lO[r]);
    }
}

// ---------------------------------------------------------------------------
// Phase 3: out = sa @ Wp + bp   (m97 128^2 structure, fp32 out)
// ---------------------------------------------------------------------------
__global__ __launch_bounds__(256)
void out_gemm(const bf16_t* __restrict__ A, const bf16_t* __restrict__ Bt,
              const float* __restrict__ bp, float* __restrict__ out) {
  const int mb = blockIdx.x, nb = blockIdx.y;
  const int t = threadIdx.x;
  const int w = t >> 6, l = t & 63, l15 = l & 15, lg = l >> 4;
  const int wr = (w >> 1) * 64, wc = (w & 1) * 64;

  __shared__ bf16_t As[128 * 64];
  __shared__ bf16_t Bs[128 * 64];

  const int srow = w * 32 + (l >> 3);
  const int scol = (l & 7) * 8;
  const bf16_t* ag = A + (size_t)(mb * 128 + srow) * D_ + scol;
  const bf16_t* bg = Bt + (size_t)(nb * 128 + srow) * D_ + scol;
  char* asl = (char*)As + w * 4096;
  char* bsl = (char*)Bs + w * 4096;

  f32x4 acc[4][4] = {};

  for (int kb = 0; kb < 16; ++kb) {
    __syncthreads();
    #pragma unroll
    for (int i = 0; i < 4; ++i) {
      gload_lds16(ag + (size_t)i * 8 * D_ + kb * 64, asl + i * 1024);
      gload_lds16(bg + (size_t)i * 8 * D_ + kb * 64, bsl + i * 1024);
    }
    __syncthreads();
    #pragma unroll
    for (int ks = 0; ks < 2; ++ks) {
      bf16x8 a[4], b[4];
      #pragma unroll
      for (int mi = 0; mi < 4; ++mi)
        a[mi] = *(const bf16x8*)((const char*)As + (wr + mi * 16 + l15) * 128 + ks * 64 + lg * 16);
      #pragma unroll
      for (int ni = 0; ni < 4; ++ni)
        b[ni] = *(const bf16x8*)((const char*)Bs + (wc + ni * 16 + l15) * 128 + ks * 64 + lg * 16);
      #pragma unroll
      for (int mi = 0; mi < 4; ++mi)
        #pragma unroll
        for (int ni = 0; ni < 4; ++ni)
          acc[mi][ni] = __builtin_amdgcn_mfma_f32_16x16x32_bf16(a[mi], b[ni], acc[mi][ni], 0, 0, 0);
    }
  }

  #pragma unroll
  for (int ni = 0; ni < 4; ++ni) {
    int e = nb * 128 + wc + ni * 16 + l15;
    float bias = bp[e];
    #pragma unroll
    for (int mi = 0; mi < 4; ++mi)
      #pragma unroll
      for (int r = 0; r < 4; ++r) {
        int grow = mb * 128 + wr + mi * 16 + lg * 4 + r;
        out[(size_t)grow * D_ + e] = acc[mi][ni][r] + bias;
      }
  }
}

// ---------------------------------------------------------------------------
extern "C" void kernel_launch(void* const* d_in, const int* in_sizes, int n_in,
                              void* d_out, int out_size, void* d_ws, size_t ws_size,
                              hipStream_t stream) {
  const float* x    = (const float*)d_in[0];
  const float* Wkqv = (const float*)d_in[1];
  const float* bkqv = (const float*)d_in[2];
  const float* Wp   = (const float*)d_in[3];
  const float* bp   = (const float*)d_in[4];
  float* out = (float*)d_out;
  char* ws = (char*)d_ws;

  const size_t MB = 1 << 20;
  bf16_t* xb  = (bf16_t*)(ws);             //   8 MiB
  bf16_t* sa  = (bf16_t*)(ws + 8 * MB);    //   8 MiB
  bf16_t* Wpt = (bf16_t*)(ws + 16 * MB);   //   2 MiB
  bf16_t* Vt  = (bf16_t*)(ws + 18 * MB);   //   8 MiB
  bf16_t* Qc  = (bf16_t*)(ws + 26 * MB);   //  64 MiB (32 bh)
  bf16_t* Kc  = (bf16_t*)(ws + 90 * MB);   //  64 MiB (32 bh)
  bf16_t* Wt  = (bf16_t*)(ws + 154 * MB);  //  32 MiB (8 heads x 2048 x 1024)
  bf16_t* Wvt = (bf16_t*)(ws + 186 * MB);  //   2 MiB (16 heads x 64 x 1024)
  float*  SgC = (float*) (ws + 188 * MB);  //  80 MiB
  // total 268 MiB (< proven-safe 285,212,672 B)

  hipLaunchKernelGGL(conv_x, dim3(1024), dim3(256), 0, stream, x, xb);
  hipLaunchKernelGGL(conv_wp, dim3(32, 32), dim3(256), 0, stream, Wp, Wpt);
  hipLaunchKernelGGL(conv_wv, dim3(2, 32, 16), dim3(256), 0, stream, Wkqv, Wvt);
  hipLaunchKernelGGL(v_gemm, dim3(32, 16), dim3(256), 0, stream, xb, Wvt, bkqv, Vt);

  for (int c = 0; c < 2; ++c) {
    hipLaunchKernelGGL(conv_wkqv, dim3(64, 32, 8), dim3(256), 0, stream,
                       Wkqv, Wt, c * 8);
    hipLaunchKernelGGL(kqv256, dim3(16, 8, 8), dim3(512), 0, stream,
                       xb, Wt, bkqv, c * 8, Kc, Qc);
    hipLaunchKernelGGL(s_gemm256, dim3(10, 32), dim3(512), 0, stream,
                       Qc, Kc, SgC);
    hipLaunchKernelGGL(softmax_pv, dim3(16, 32), dim3(256), 0, stream,
                       SgC, Vt, sa, c);
  }

  hipLaunchKernelGGL(out_gemm, dim3(32, 8), dim3(256), 0, stream, sa, Wpt, bp, out);
}

// Round 6
// 617.024 us; speedup vs baseline: 4.2334x; 1.0787x over previous
//
#include <hip/hip_runtime.h>
#include <hip/hip_bf16.h>

#define B_ 4
#define N_ 1024
#define D_ 1024
#define H_ 16
#define DH_ 64
#define E_ 2112
#define ROWS_ 4096

typedef __bf16 bf16_t;
typedef bf16_t bf16x4 __attribute__((ext_vector_type(4)));
typedef bf16_t bf16x8 __attribute__((ext_vector_type(8)));
typedef float f32x4 __attribute__((ext_vector_type(4)));

__device__ __forceinline__ void gload_lds16(const void* g, void* l) {
  __builtin_amdgcn_global_load_lds(
      (const __attribute__((address_space(1))) void*)g,
      (__attribute__((address_space(3))) void*)l, 16, 0, 0);
}

// ---------------------------------------------------------------------------
// conversion passes
// ---------------------------------------------------------------------------
__global__ __launch_bounds__(256)
void conv_x(const float* __restrict__ x, bf16_t* __restrict__ xb) {
  const int n4 = ROWS_ * D_ / 4;
  for (int i = blockIdx.x * 256 + threadIdx.x; i < n4; i += gridDim.x * 256) {
    float4 v = ((const float4*)x)[i];
    bf16x4 o = {(bf16_t)v.x, (bf16_t)v.y, (bf16_t)v.z, (bf16_t)v.w};
    ((bf16x4*)xb)[i] = o;
  }
}

// W[h][d][e] fp32 -> Wt[hz][e][d] bf16 for e in [0,2048), 8 heads.
// 64x64 tile: float4 reads, scalar LDS (pad 65, 2-way max), bf16x8 writes.
__global__ __launch_bounds__(256)
void conv_wkqv(const float* __restrict__ W, bf16_t* __restrict__ Wt, int h0) {
  const int et = blockIdx.x, dt = blockIdx.y, hz = blockIdx.z;
  const float* Wh = W + (size_t)(h0 + hz) * D_ * E_;
  __shared__ float tile[64][65];
  const int t = threadIdx.x;
  const int drow = t >> 4, e4 = (t & 15) * 4;
  #pragma unroll
  for (int i = 0; i < 4; ++i) {
    int d = dt * 64 + drow + i * 16;
    float4 v = *(const float4*)(Wh + (size_t)d * E_ + et * 64 + e4);
    tile[drow + i * 16][e4 + 0] = v.x;
    tile[drow + i * 16][e4 + 1] = v.y;
    tile[drow + i * 16][e4 + 2] = v.z;
    tile[drow + i * 16][e4 + 3] = v.w;
  }
  __syncthreads();
  const int erow = t >> 3, d8 = (t & 7) * 8;
  bf16_t* Wto = Wt + (size_t)hz * 2048 * D_;
  #pragma unroll
  for (int i = 0; i < 2; ++i) {
    int e = erow + i * 32;
    bf16x8 o;
    #pragma unroll
    for (int j = 0; j < 8; ++j) o[j] = (bf16_t)tile[d8 + j][e];
    *(bf16x8*)(Wto + (size_t)(et * 64 + e) * D_ + dt * 64 + d8) = o;
  }
}

// W[h][d][2048+dh] fp32 -> Wvt[h][dh][d] bf16 (all 16 heads)
__global__ __launch_bounds__(256)
void conv_wv(const float* __restrict__ W, bf16_t* __restrict__ Wvt) {
  const int et = blockIdx.x, dt = blockIdx.y, h = blockIdx.z;
  const int tx = threadIdx.x & 31, ty = threadIdx.x >> 5;
  __shared__ float tile[32][33];
  const float* Wh = W + (size_t)h * D_ * E_;
  #pragma unroll
  for (int rr = 0; rr < 4; ++rr) {
    int d = dt * 32 + rr * 8 + ty;
    int dh = et * 32 + tx;
    tile[rr * 8 + ty][tx] = Wh[(size_t)d * E_ + 2048 + dh];
  }
  __syncthreads();
  bf16_t* Wvo = Wvt + (size_t)h * DH_ * D_;
  #pragma unroll
  for (int rr = 0; rr < 4; ++rr) {
    int dh = et * 32 + rr * 8 + ty;
    int d = dt * 32 + tx;
    Wvo[(size_t)dh * D_ + d] = (bf16_t)tile[tx][rr * 8 + ty];
  }
}

// Wp[k][n] fp32 -> Wpt[n][k] bf16
__global__ __launch_bounds__(256)
void conv_wp(const float* __restrict__ Wp, bf16_t* __restrict__ Wpt) {
  const int nt = blockIdx.x, kt = blockIdx.y;
  const int tx = threadIdx.x & 31, ty = threadIdx.x >> 5;
  __shared__ float tile[32][33];
  #pragma unroll
  for (int rr = 0; rr < 4; ++rr)
    tile[rr * 8 + ty][tx] = Wp[(size_t)(kt * 32 + rr * 8 + ty) * D_ + nt * 32 + tx];
  __syncthreads();
  #pragma unroll
  for (int rr = 0; rr < 4; ++rr)
    Wpt[(size_t)(nt * 32 + rr * 8 + ty) * D_ + kt * 32 + tx] = (bf16_t)tile[tx][rr * 8 + ty];
}

// ---------------------------------------------------------------------------
// 256x256xK=1024 phase-split MFMA core (unchanged from r5).
// ---------------------------------------------------------------------------
__device__ __forceinline__ void mm256_core(const bf16_t* __restrict__ Ag,
                                           const bf16_t* __restrict__ Bg,
                                           bf16_t* lds, f32x4 (&acc)[8][4]) {
  bf16_t* Asp = lds;           // [2][16384]
  bf16_t* Bsp = lds + 32768;   // [2][16384]
  const int t = threadIdx.x;
  const int w = t >> 6, l = t & 63, l15 = l & 15, lg = l >> 4;
  const int wm = w >> 2, wn = w & 3;

  const int srow = w * 8 + (l >> 3);
  const int scol = (((l & 7) ^ (l >> 3)) << 3);
  const bf16_t* aS = Ag + (size_t)srow * 1024 + scol;
  const bf16_t* bS = Bg + (size_t)srow * 1024 + scol;

#define STG2_(SRC, BASE, bufi, kt, hh)                                         \
  do {                                                                         \
    gload_lds16((SRC) + (size_t)((hh) * 128) * 1024 + (kt) * 64,               \
                (char*)(BASE) + (bufi) * 32768 + (hh) * 16384 + w * 1024);     \
    gload_lds16((SRC) + (size_t)((hh) * 128 + 64) * 1024 + (kt) * 64,          \
                (char*)(BASE) + (bufi) * 32768 + (hh) * 16384 + 8192 + w * 1024); \
  } while (0)

  STG2_(bS, Bsp, 0, 0, 0);
  STG2_(bS, Bsp, 0, 0, 1);
  STG2_(aS, Asp, 0, 0, 0);
  STG2_(aS, Asp, 0, 0, 1);
  asm volatile("s_waitcnt vmcnt(0)" ::: "memory");
  __builtin_amdgcn_s_barrier();

  const int rswz = (l15 & 7) << 4;

  for (int kt = 0; kt < 16; ++kt) {
    const char* Ab = (const char*)Asp + (kt & 1) * 32768 + wm * 16384;
    const char* Bb = (const char*)Bsp + (kt & 1) * 32768 + (wn >> 1) * 16384;
    const int nkt = kt + 1;
    bf16x8 b[4];
    #pragma unroll
    for (int ph = 0; ph < 4; ++ph) {
      const int ks = ph >> 1, mh = ph & 1;
      const int cswz = (ks * 64 + lg * 16) ^ rswz;
      if (mh == 0) {
        #pragma unroll
        for (int ni = 0; ni < 4; ++ni)
          b[ni] = *(const bf16x8*)(Bb + ((wn & 1) * 64 + ni * 16 + l15) * 128 + cswz);
      }
      bf16x8 a[4];
      #pragma unroll
      for (int mi = 0; mi < 4; ++mi)
        a[mi] = *(const bf16x8*)(Ab + (mh * 64 + mi * 16 + l15) * 128 + cswz);
      if (nkt < 16 && ph == 0) {
        STG2_(bS, Bsp, nkt & 1, nkt, 0);
        STG2_(bS, Bsp, nkt & 1, nkt, 1);
        STG2_(aS, Asp, nkt & 1, nkt, 0);
        STG2_(aS, Asp, nkt & 1, nkt, 1);
      }
      __builtin_amdgcn_s_barrier();
      asm volatile("s_waitcnt lgkmcnt(0)" ::: "memory");
      __builtin_amdgcn_s_setprio(1);
      #pragma unroll
      for (int mi = 0; mi < 4; ++mi)
        #pragma unroll
        for (int ni = 0; ni < 4; ++ni)
          acc[mh * 4 + mi][ni] = __builtin_amdgcn_mfma_f32_16x16x32_bf16(
              a[mi], b[ni], acc[mh * 4 + mi][ni], 0, 0, 0);
      __builtin_amdgcn_s_setprio(0);
      if (ph == 3) asm volatile("s_waitcnt vmcnt(0)" ::: "memory");
      __builtin_amdgcn_s_barrier();
    }
  }
#undef STG2_
}

// chunk-XOR for the epilogue transpose: 16B chunk c -> c ^ (c>>3), bijective.
__device__ __forceinline__ int xchunk4(int colf) {
  int c = colf >> 2;
  return ((c ^ (c >> 3)) << 2) | (colf & 3);
}

// ---------------------------------------------------------------------------
// Phase 1: [K|Q] = x @ Wkqv[h][:, :2048] + b for 8 heads. 256^2 core.
// 1D grid, XCD-swizzled decode. Epilogue: bias, LDS transpose (chunk-XOR),
// coalesced bf16x8 stores.
// ---------------------------------------------------------------------------
__global__ __launch_bounds__(512)
void kqv256(const bf16_t* __restrict__ xb, const bf16_t* __restrict__ Wt,
            const float* __restrict__ bkqv, int h0,
            bf16_t* __restrict__ Kc, bf16_t* __restrict__ Qc) {
  __shared__ bf16_t lds[65536];
  // XCD swizzle: 1024 blocks, cpx=128; lid: mb fastest, then nb, then hz.
  const int bid = blockIdx.x;
  const int lid = (bid & 7) * 128 + (bid >> 3);
  const int mb = lid & 15, nb = (lid >> 4) & 7, hz = lid >> 7;

  f32x4 acc[8][4] = {};
  mm256_core(xb + (size_t)mb * 256 * D_,
             Wt + ((size_t)hz * 2048 + (size_t)nb * 256) * D_, lds, acc);

  const int t = threadIdx.x;
  const int w = t >> 6, l = t & 63, l15 = l & 15, lg = l >> 4;
  const int wm = w >> 2, wn = w & 3;
  const int h = h0 + hz;

  float bias[4];
  #pragma unroll
  for (int ni = 0; ni < 4; ++ni)
    bias[ni] = bkqv[h * E_ + nb * 256 + wn * 64 + ni * 16 + l15];
  #pragma unroll
  for (int mi = 0; mi < 8; ++mi)
    #pragma unroll
    for (int ni = 0; ni < 4; ++ni)
      #pragma unroll
      for (int r = 0; r < 4; ++r) acc[mi][ni][r] += bias[ni];

  float* Ct = (float*)lds;   // [64][258], cols chunk-XOR swizzled
  const int cpair = t & 31;
  const int p0 = xchunk4(cpair * 8);
  const int p1 = xchunk4(cpair * 8 + 4);
  #pragma unroll
  for (int s = 0; s < 4; ++s) {
    __syncthreads();
    #pragma unroll
    for (int m2 = 0; m2 < 2; ++m2)
      #pragma unroll
      for (int ni = 0; ni < 4; ++ni)
        #pragma unroll
        for (int r = 0; r < 4; ++r)
          Ct[(wm * 32 + m2 * 16 + lg * 4 + r) * 258 +
             xchunk4(wn * 64 + ni * 16 + l15)] = acc[2 * s + m2][ni][r];
    __syncthreads();
    #pragma unroll
    for (int it = 0; it < 4; ++it) {
      int row64 = (t >> 5) + it * 16;
      int wmq = row64 >> 5, m2q = (row64 >> 4) & 1, r16 = row64 & 15;
      int c8 = cpair * 8;
      const float* r0 = &Ct[row64 * 258 + p0];
      const float* r1 = &Ct[row64 * 258 + p1];
      bf16x8 o = {(bf16_t)r0[0], (bf16_t)r0[1], (bf16_t)r0[2], (bf16_t)r0[3],
                  (bf16_t)r1[0], (bf16_t)r1[1], (bf16_t)r1[2], (bf16_t)r1[3]};
      int grow = mb * 256 + wmq * 128 + (2 * s + m2q) * 16 + r16;
      int b = grow >> 10, n = grow & (N_ - 1);
      int bhl = b * 8 + hz;
      size_t base = ((size_t)bhl * N_ + n) * D_;
      if (nb < 4)
        *(bf16x8*)(Kc + base + nb * 256 + c8) = o;
      else
        *(bf16x8*)(Qc + base + nb * 256 - 1024 + c8) = o;
    }
  }
}

// ---------------------------------------------------------------------------
// Phase 2a: S = scale * Q.K^T, lower-triangle 256x256 tiles (10 per bh).
// 1D grid, XCD-swizzled. Epilogue: scale+mask, chunk-XOR transpose, f32 out.
// ---------------------------------------------------------------------------
__global__ __launch_bounds__(512)
void s_gemm256(const bf16_t* __restrict__ Qc, const bf16_t* __restrict__ Kc,
               float* __restrict__ SgC) {
  __shared__ bf16_t lds[65536];
  // XCD swizzle: 320 blocks, cpx=40; idx fastest -> 4 bh per XCD.
  const int bid = blockIdx.x;
  const int lid = (bid & 7) * 40 + (bid >> 3);
  const int idx = lid % 10;   // 0..9 lower-triangle tile
  const int bhl = lid / 10;   // 0..31
  int qt = 0;
  while ((qt + 1) * (qt + 2) / 2 <= idx) ++qt;
  const int kt = idx - qt * (qt + 1) / 2;

  f32x4 acc[8][4] = {};
  mm256_core(Qc + ((size_t)bhl * N_ + (size_t)qt * 256) * D_,
             Kc + ((size_t)bhl * N_ + (size_t)kt * 256) * D_, lds, acc);

  const int t = threadIdx.x;
  const int w = t >> 6, l = t & 63, l15 = l & 15, lg = l >> 4;
  const int wm = w >> 2, wn = w & 3;
  const float SCALE = 0.045084220027780106f;   // log2(e)/sqrt(1024)
  float* So = SgC + (((size_t)bhl * 10 + idx) << 16);

  #pragma unroll
  for (int mi = 0; mi < 8; ++mi)
    #pragma unroll
    for (int ni = 0; ni < 4; ++ni)
      #pragma unroll
      for (int r = 0; r < 4; ++r) {
        int rl = wm * 128 + mi * 16 + lg * 4 + r;
        int cl = wn * 64 + ni * 16 + l15;
        float z = acc[mi][ni][r] * SCALE;
        if (kt * 256 + cl > qt * 256 + rl) z = -1e30f;
        acc[mi][ni][r] = z;
      }

  float* Ct = (float*)lds;   // [64][258], chunk-XOR swizzled
  const int cpair = t & 31;
  const int p0 = xchunk4(cpair * 8);
  const int p1 = xchunk4(cpair * 8 + 4);
  #pragma unroll
  for (int s = 0; s < 4; ++s) {
    __syncthreads();
    #pragma unroll
    for (int m2 = 0; m2 < 2; ++m2)
      #pragma unroll
      for (int ni = 0; ni < 4; ++ni)
        #pragma unroll
        for (int r = 0; r < 4; ++r)
          Ct[(wm * 32 + m2 * 16 + lg * 4 + r) * 258 +
             xchunk4(wn * 64 + ni * 16 + l15)] = acc[2 * s + m2][ni][r];
    __syncthreads();
    #pragma unroll
    for (int it = 0; it < 4; ++it) {
      int row64 = (t >> 5) + it * 16;
      int wmq = row64 >> 5, m2q = (row64 >> 4) & 1, r16 = row64 & 15;
      int c8 = cpair * 8;
      const float* r0 = &Ct[row64 * 258 + p0];
      const float* r1 = &Ct[row64 * 258 + p1];
      float4 v0 = {r0[0], r0[1], r0[2], r0[3]};
      float4 v1 = {r1[0], r1[1], r1[2], r1[3]};
      int rl = wmq * 128 + (2 * s + m2q) * 16 + r16;
      *(float4*)(So + (size_t)rl * 256 + c8) = v0;
      *(float4*)(So + (size_t)rl * 256 + c8 + 4) = v1;
    }
  }
}

// ---------------------------------------------------------------------------
// V gemm (unchanged): Vt[bh][dh][n] = Wv^T @ x^T + bias.
// ---------------------------------------------------------------------------
__global__ __launch_bounds__(256)
void v_gemm(const bf16_t* __restrict__ xb, const bf16_t* __restrict__ Wvt,
            const float* __restrict__ bkqv, bf16_t* __restrict__ Vt) {
  const int nt = blockIdx.x;   // 0..31
  const int h = blockIdx.y;    // 0..15
  const int t = threadIdx.x;
  const int w = t >> 6, l = t & 63, l15 = l & 15, lg = l >> 4;

  __shared__ bf16_t As2[64 * 64];
  __shared__ bf16_t Bs2[128 * 64];
  const bf16_t* Wvh = Wvt + (size_t)h * DH_ * D_;
  const bf16_t* Bn = xb + (size_t)nt * 128 * D_;

  f32x4 acc[4][2] = {};
  const int rswz = (l15 & 7) << 4;

  for (int kb = 0; kb < 16; ++kb) {
    __syncthreads();
    #pragma unroll
    for (int i = 0; i < 2; ++i) {
      int idx = t + i * 256;
      int row = idx >> 3, c = idx & 7;
      gload_lds16(Wvh + (size_t)row * D_ + kb * 64 + ((c ^ (row & 7)) << 3),
                  (char*)As2 + idx * 16);
    }
    #pragma unroll
    for (int i = 0; i < 4; ++i) {
      int idx = t + i * 256;
      int row = idx >> 3, c = idx & 7;
      gload_lds16(Bn + (size_t)row * D_ + kb * 64 + ((c ^ (row & 7)) << 3),
                  (char*)Bs2 + idx * 16);
    }
    __syncthreads();
    #pragma unroll
    for (int ks = 0; ks < 2; ++ks) {
      const int cswz = (ks * 64 + lg * 16) ^ rswz;
      bf16x8 a[4], b[2];
      #pragma unroll
      for (int mi = 0; mi < 4; ++mi)
        a[mi] = *(const bf16x8*)((const char*)As2 + (mi * 16 + l15) * 128 + cswz);
      #pragma unroll
      for (int ni = 0; ni < 2; ++ni)
        b[ni] = *(const bf16x8*)((const char*)Bs2 + (w * 32 + ni * 16 + l15) * 128 + cswz);
      #pragma unroll
      for (int mi = 0; mi < 4; ++mi)
        #pragma unroll
        for (int ni = 0; ni < 2; ++ni)
          acc[mi][ni] = __builtin_amdgcn_mfma_f32_16x16x32_bf16(a[mi], b[ni], acc[mi][ni], 0, 0, 0);
    }
  }

  #pragma unroll
  for (int mi = 0; mi < 4; ++mi)
    #pragma unroll
    for (int r = 0; r < 4; ++r) {
      int dh = mi * 16 + lg * 4 + r;
      float bias = bkqv[h * E_ + 2048 + dh];
      #pragma unroll
      for (int ni = 0; ni < 2; ++ni) {
        int nn = nt * 128 + w * 32 + ni * 16 + l15;
        int b = nn >> 10, n = nn & (N_ - 1);
        int bh = b * H_ + h;
        Vt[((size_t)bh * DH_ + dh) * N_ + n] = (bf16_t)(acc[mi][ni][r] + bias);
      }
    }
}

// ---------------------------------------------------------------------------
// Phase 2b: softmax + P.V (unchanged).
// ---------------------------------------------------------------------------
__global__ __launch_bounds__(256)
void softmax_pv(const float* __restrict__ SgC, const bf16_t* __restrict__ Vt,
                bf16_t* __restrict__ sa, int c) {
  const int qt = blockIdx.x;   // 0..15
  const int bhl = blockIdx.y;  // 0..31
  const int t = threadIdx.x;
  const int w = t >> 6, l = t & 63, l15 = l & 15, lg = l >> 4;
  const int b = bhl >> 3, h = c * 8 + (bhl & 7);
  const int bh = b * H_ + h;

  const int qrow = qt * 64 + w * 16 + l15;
  const int qt8 = qt >> 2;
  const float* Sbh = SgC + (((size_t)bhl * 10) << 16);
  const bf16_t* Vh = Vt + (size_t)bh * DH_ * N_;

  f32x4 accO[4] = {};
  float m = -1e30f, lsum = 0.f;

  for (int j = 0; j <= qt; ++j) {
    const int jb = j * 64;
    const int tid = qt8 * (qt8 + 1) / 2 + (j >> 2);
    const float* Srow = Sbh + ((size_t)tid << 16) + (size_t)(qrow & 255) * 256 + (jb & 255);

    float4 sA = *(const float4*)(Srow + lg * 8);
    float4 sB = *(const float4*)(Srow + lg * 8 + 4);
    float4 sC = *(const float4*)(Srow + 32 + lg * 8);
    float4 sD = *(const float4*)(Srow + 32 + lg * 8 + 4);

    float zm = fmaxf(fmaxf(fmaxf(sA.x, sA.y), fmaxf(sA.z, sA.w)),
                     fmaxf(fmaxf(sB.x, sB.y), fmaxf(sB.z, sB.w)));
    zm = fmaxf(zm, fmaxf(fmaxf(fmaxf(sC.x, sC.y), fmaxf(sC.z, sC.w)),
                         fmaxf(fmaxf(sD.x, sD.y), fmaxf(sD.z, sD.w))));
    zm = fmaxf(zm, __shfl_xor(zm, 16));
    zm = fmaxf(zm, __shfl_xor(zm, 32));

    float mnew = fmaxf(m, zm);
    float scl = exp2f(m - mnew);
    m = mnew;

    float p[16];
    p[0] = exp2f(sA.x - mnew); p[1] = exp2f(sA.y - mnew);
    p[2] = exp2f(sA.z - mnew); p[3] = exp2f(sA.w - mnew);
    p[4] = exp2f(sB.x - mnew); p[5] = exp2f(sB.y - mnew);
    p[6] = exp2f(sB.z - mnew); p[7] = exp2f(sB.w - mnew);
    p[8] = exp2f(sC.x - mnew); p[9] = exp2f(sC.y - mnew);
    p[10] = exp2f(sC.z - mnew); p[11] = exp2f(sC.w - mnew);
    p[12] = exp2f(sD.x - mnew); p[13] = exp2f(sD.y - mnew);
    p[14] = exp2f(sD.z - mnew); p[15] = exp2f(sD.w - mnew);

    float rs = 0.f;
    #pragma unroll
    for (int i = 0; i < 16; ++i) rs += p[i];
    rs += __shfl_xor(rs, 16);
    rs += __shfl_xor(rs, 32);
    lsum = lsum * scl + rs;

    float sclO[4];
    #pragma unroll
    for (int r = 0; r < 4; ++r) sclO[r] = __shfl(scl, lg * 4 + r);
    #pragma unroll
    for (int db = 0; db < 4; ++db)
      #pragma unroll
      for (int r = 0; r < 4; ++r) accO[db][r] *= sclO[r];

    bf16x8 pa0 = {(bf16_t)p[0], (bf16_t)p[1], (bf16_t)p[2], (bf16_t)p[3],
                  (bf16_t)p[4], (bf16_t)p[5], (bf16_t)p[6], (bf16_t)p[7]};
    bf16x8 pa1 = {(bf16_t)p[8], (bf16_t)p[9], (bf16_t)p[10], (bf16_t)p[11],
                  (bf16_t)p[12], (bf16_t)p[13], (bf16_t)p[14], (bf16_t)p[15]};

    #pragma unroll
    for (int db = 0; db < 4; ++db) {
      const bf16_t* vp = Vh + (size_t)(db * 16 + l15) * N_ + jb;
      bf16x8 vb0 = *(const bf16x8*)(vp + lg * 8);
      bf16x8 vb1 = *(const bf16x8*)(vp + 32 + lg * 8);
      accO[db] = __builtin_amdgcn_mfma_f32_16x16x32_bf16(pa0, vb0, accO[db], 0, 0, 0);
      accO[db] = __builtin_amdgcn_mfma_f32_16x16x32_bf16(pa1, vb1, accO[db], 0, 0, 0);
    }
  }

  float lO[4];
  #pragma unroll
  for (int r = 0; r < 4; ++r) lO[r] = __shfl(lsum, lg * 4 + r);

  #pragma unroll
  for (int db = 0; db < 4; ++db)
    #pragma unroll
    for (int r = 0; r < 4; ++r) {
      int row = qt * 64 + w * 16 + lg * 4 + r;
      int col = h * DH_ + db * 16 + l15;
      sa[((size_t)b * N_ + row) * D_ + col] = (bf16_t)(accO[db][r] / lO[r]);
    }
}

// ---------------------------------------------------------------------------
// Phase 3: out = sa @ Wp + bp   (m97 128^2 structure, fp32 out)
// ---------------------------------------------------------------------------
__global__ __launch_bounds__(256)
void out_gemm(const bf16_t* __restrict__ A, const bf16_t* __restrict__ Bt,
              const float* __restrict__ bp, float* __restrict__ out) {
  const int mb = blockIdx.x, nb = blockIdx.y;
  const int t = threadIdx.x;
  const int w = t >> 6, l = t & 63, l15 = l & 15, lg = l >> 4;
  const int wr = (w >> 1) * 64, wc = (w & 1) * 64;

  __shared__ bf16_t As[128 * 64];
  __shared__ bf16_t Bs[128 * 64];

  const int srow = w * 32 + (l >> 3);
  const int scol = (l & 7) * 8;
  const bf16_t* ag = A + (size_t)(mb * 128 + srow) * D_ + scol;
  const bf16_t* bg = Bt + (size_t)(nb * 128 + srow) * D_ + scol;
  char* asl = (char*)As + w * 4096;
  char* bsl = (char*)Bs + w * 4096;

  f32x4 acc[4][4] = {};

  for (int kb = 0; kb < 16; ++kb) {
    __syncthreads();
    #pragma unroll
    for (int i = 0; i < 4; ++i) {
      gload_lds16(ag + (size_t)i * 8 * D_ + kb * 64, asl + i * 1024);
      gload_lds16(bg + (size_t)i * 8 * D_ + kb * 64, bsl + i * 1024);
    }
    __syncthreads();
    #pragma unroll
    for (int ks = 0; ks < 2; ++ks) {
      bf16x8 a[4], b[4];
      #pragma unroll
      for (int mi = 0; mi < 4; ++mi)
        a[mi] = *(const bf16x8*)((const char*)As + (wr + mi * 16 + l15) * 128 + ks * 64 + lg * 16);
      #pragma unroll
      for (int ni = 0; ni < 4; ++ni)
        b[ni] = *(const bf16x8*)((const char*)Bs + (wc + ni * 16 + l15) * 128 + ks * 64 + lg * 16);
      #pragma unroll
      for (int mi = 0; mi < 4; ++mi)
        #pragma unroll
        for (int ni = 0; ni < 4; ++ni)
          acc[mi][ni] = __builtin_amdgcn_mfma_f32_16x16x32_bf16(a[mi], b[ni], acc[mi][ni], 0, 0, 0);
    }
  }

  #pragma unroll
  for (int ni = 0; ni < 4; ++ni) {
    int e = nb * 128 + wc + ni * 16 + l15;
    float bias = bp[e];
    #pragma unroll
    for (int mi = 0; mi < 4; ++mi)
      #pragma unroll
      for (int r = 0; r < 4; ++r) {
        int grow = mb * 128 + wr + mi * 16 + lg * 4 + r;
        out[(size_t)grow * D_ + e] = acc[mi][ni][r] + bias;
      }
  }
}

// ---------------------------------------------------------------------------
extern "C" void kernel_launch(void* const* d_in, const int* in_sizes, int n_in,
                              void* d_out, int out_size, void* d_ws, size_t ws_size,
                              hipStream_t stream) {
  const float* x    = (const float*)d_in[0];
  const float* Wkqv = (const float*)d_in[1];
  const float* bkqv = (const float*)d_in[2];
  const float* Wp   = (const float*)d_in[3];
  const float* bp   = (const float*)d_in[4];
  float* out = (float*)d_out;
  char* ws = (char*)d_ws;

  const size_t MB = 1 << 20;
  bf16_t* xb  = (bf16_t*)(ws);             //   8 MiB
  bf16_t* sa  = (bf16_t*)(ws + 8 * MB);    //   8 MiB
  bf16_t* Wpt = (bf16_t*)(ws + 16 * MB);   //   2 MiB
  bf16_t* Vt  = (bf16_t*)(ws + 18 * MB);   //   8 MiB
  bf16_t* Qc  = (bf16_t*)(ws + 26 * MB);   //  64 MiB (32 bh)
  bf16_t* Kc  = (bf16_t*)(ws + 90 * MB);   //  64 MiB (32 bh)
  bf16_t* Wt  = (bf16_t*)(ws + 154 * MB);  //  32 MiB (8 heads x 2048 x 1024)
  bf16_t* Wvt = (bf16_t*)(ws + 186 * MB);  //   2 MiB
  float*  SgC = (float*) (ws + 188 * MB);  //  80 MiB
  // total 268 MiB (< proven-safe 285,212,672 B)

  hipLaunchKernelGGL(conv_x, dim3(1024), dim3(256), 0, stream, x, xb);
  hipLaunchKernelGGL(conv_wp, dim3(32, 32), dim3(256), 0, stream, Wp, Wpt);
  hipLaunchKernelGGL(conv_wv, dim3(2, 32, 16), dim3(256), 0, stream, Wkqv, Wvt);
  hipLaunchKernelGGL(v_gemm, dim3(32, 16), dim3(256), 0, stream, xb, Wvt, bkqv, Vt);

  for (int c = 0; c < 2; ++c) {
    hipLaunchKernelGGL(conv_wkqv, dim3(32, 16, 8), dim3(256), 0, stream,
                       Wkqv, Wt, c * 8);
    hipLaunchKernelGGL(kqv256, dim3(1024), dim3(512), 0, stream,
                       xb, Wt, bkqv, c * 8, Kc, Qc);
    hipLaunchKernelGGL(s_gemm256, dim3(320), dim3(512), 0, stream,
                       Qc, Kc, SgC);
    hipLaunchKernelGGL(softmax_pv, dim3(16, 32), dim3(256), 0, stream,
                       SgC, Vt, sa, c);
  }

  hipLaunchKernelGGL(out_gemm, dim3(32, 8), dim3(256), 0, stream, sa, Wpt, bp, out);
}

// Round 7
// 574.598 us; speedup vs baseline: 4.5460x; 1.0738x over previous
//
#include <hip/hip_runtime.h>
#include <hip/hip_bf16.h>

#define B_ 4
#define N_ 1024
#define D_ 1024
#define H_ 16
#define DH_ 64
#define E_ 2112
#define ROWS_ 4096

typedef __bf16 bf16_t;
typedef bf16_t bf16x4 __attribute__((ext_vector_type(4)));
typedef bf16_t bf16x8 __attribute__((ext_vector_type(8)));
typedef float f32x4 __attribute__((ext_vector_type(4)));

__device__ __forceinline__ void gload_lds16(const void* g, void* l) {
  __builtin_amdgcn_global_load_lds(
      (const __attribute__((address_space(1))) void*)g,
      (__attribute__((address_space(3))) void*)l, 16, 0, 0);
}

// ---------------------------------------------------------------------------
// conversion passes (unchanged)
// ---------------------------------------------------------------------------
__global__ __launch_bounds__(256)
void conv_x(const float* __restrict__ x, bf16_t* __restrict__ xb) {
  const int n4 = ROWS_ * D_ / 4;
  for (int i = blockIdx.x * 256 + threadIdx.x; i < n4; i += gridDim.x * 256) {
    float4 v = ((const float4*)x)[i];
    bf16x4 o = {(bf16_t)v.x, (bf16_t)v.y, (bf16_t)v.z, (bf16_t)v.w};
    ((bf16x4*)xb)[i] = o;
  }
}

__global__ __launch_bounds__(256)
void conv_wkqv(const float* __restrict__ W, bf16_t* __restrict__ Wt, int h0) {
  const int et = blockIdx.x, dt = blockIdx.y, hz = blockIdx.z;
  const float* Wh = W + (size_t)(h0 + hz) * D_ * E_;
  __shared__ float tile[64][65];
  const int t = threadIdx.x;
  const int drow = t >> 4, e4 = (t & 15) * 4;
  #pragma unroll
  for (int i = 0; i < 4; ++i) {
    int d = dt * 64 + drow + i * 16;
    float4 v = *(const float4*)(Wh + (size_t)d * E_ + et * 64 + e4);
    tile[drow + i * 16][e4 + 0] = v.x;
    tile[drow + i * 16][e4 + 1] = v.y;
    tile[drow + i * 16][e4 + 2] = v.z;
    tile[drow + i * 16][e4 + 3] = v.w;
  }
  __syncthreads();
  const int erow = t >> 3, d8 = (t & 7) * 8;
  bf16_t* Wto = Wt + (size_t)hz * 2048 * D_;
  #pragma unroll
  for (int i = 0; i < 2; ++i) {
    int e = erow + i * 32;
    bf16x8 o;
    #pragma unroll
    for (int j = 0; j < 8; ++j) o[j] = (bf16_t)tile[d8 + j][e];
    *(bf16x8*)(Wto + (size_t)(et * 64 + e) * D_ + dt * 64 + d8) = o;
  }
}

__global__ __launch_bounds__(256)
void conv_wv(const float* __restrict__ W, bf16_t* __restrict__ Wvt) {
  const int et = blockIdx.x, dt = blockIdx.y, h = blockIdx.z;
  const int tx = threadIdx.x & 31, ty = threadIdx.x >> 5;
  __shared__ float tile[32][33];
  const float* Wh = W + (size_t)h * D_ * E_;
  #pragma unroll
  for (int rr = 0; rr < 4; ++rr) {
    int d = dt * 32 + rr * 8 + ty;
    int dh = et * 32 + tx;
    tile[rr * 8 + ty][tx] = Wh[(size_t)d * E_ + 2048 + dh];
  }
  __syncthreads();
  bf16_t* Wvo = Wvt + (size_t)h * DH_ * D_;
  #pragma unroll
  for (int rr = 0; rr < 4; ++rr) {
    int dh = et * 32 + rr * 8 + ty;
    int d = dt * 32 + tx;
    Wvo[(size_t)dh * D_ + d] = (bf16_t)tile[tx][rr * 8 + ty];
  }
}

__global__ __launch_bounds__(256)
void conv_wp(const float* __restrict__ Wp, bf16_t* __restrict__ Wpt) {
  const int nt = blockIdx.x, kt = blockIdx.y;
  const int tx = threadIdx.x & 31, ty = threadIdx.x >> 5;
  __shared__ float tile[32][33];
  #pragma unroll
  for (int rr = 0; rr < 4; ++rr)
    tile[rr * 8 + ty][tx] = Wp[(size_t)(kt * 32 + rr * 8 + ty) * D_ + nt * 32 + tx];
  __syncthreads();
  #pragma unroll
  for (int rr = 0; rr < 4; ++rr)
    Wpt[(size_t)(nt * 32 + rr * 8 + ty) * D_ + kt * 32 + tx] = (bf16_t)tile[tx][rr * 8 + ty];
}

// ---------------------------------------------------------------------------
// 256x256xK=1024 phase-split core, COUNTED-vmcnt pipeline (T3+T4+T5).
// 8 waves (2M x 4N), BK=64, 2 LDS dbufs. Per K-tile: 4 phases x 16 MFMA.
// A halves by mi-PARITY (interleaved 16-row stripes): slot i of half h holds
// global row (i>>4)*32 + (i&15) + 16h  ->  p0/p1 consume only Ah0, p2/p3 Ah1.
// Staging (for tile kt+1, buf (kt+1)&1): p0->Bh0, p1->Bh1, p2->Ah0, p3->Ah1.
// Waits: p1-end vmcnt(4) (completes Ah1(kt), 2-phase cover);
//        p3-end vmcnt(2) (completes Bh0/Bh1/Ah0(kt+1), 1-3 phase cover).
// Main loop never drains to 0 (only kt=15 tail).
// ---------------------------------------------------------------------------
__device__ __forceinline__ void mm256_core(const bf16_t* __restrict__ Ag,
                                           const bf16_t* __restrict__ Bg,
                                           bf16_t* lds, f32x4 (&acc)[8][4]) {
  char* Asp = (char*)lds;            // [2buf][2half][128 rows][128B]
  char* Bsp = (char*)lds + 65536;
  const int t = threadIdx.x;
  const int w = t >> 6, l = t & 63, l15 = l & 15, lg = l >> 4;
  const int wm = w >> 2, wn = w & 3;

  const int lr = l >> 3;                        // 0..7
  const int scol = ((l & 7) ^ lr) << 3;         // pre-swizzled col (elems)
  // B rows: linear.  A rows: interleaved-half map (see header comment).
  const bf16_t* bS = Bg + (size_t)(w * 8 + lr) * 1024 + scol;
  const int idxA = w * 8 + lr;
  const bf16_t* aS0 = Ag + (size_t)((idxA >> 4) * 32 + (idxA & 15)) * 1024 + scol;
  const bf16_t* aS1 = aS0 + (size_t)128 * 1024;   // idx+64 -> grow+128

#define STG_B(bufi, hh, ktv)                                                   \
  do {                                                                         \
    gload_lds16(bS + (size_t)((hh) * 128) * 1024 + (ktv) * 64,                 \
                Bsp + (bufi) * 32768 + (hh) * 16384 + w * 1024);               \
    gload_lds16(bS + (size_t)((hh) * 128 + 64) * 1024 + (ktv) * 64,            \
                Bsp + (bufi) * 32768 + (hh) * 16384 + 8192 + w * 1024);        \
  } while (0)
#define STG_A(bufi, hh, ktv)                                                   \
  do {                                                                         \
    gload_lds16(aS0 + (size_t)((hh) * 16) * 1024 + (ktv) * 64,                 \
                Asp + (bufi) * 32768 + (hh) * 16384 + w * 1024);               \
    gload_lds16(aS1 + (size_t)((hh) * 16) * 1024 + (ktv) * 64,                 \
                Asp + (bufi) * 32768 + (hh) * 16384 + 8192 + w * 1024);        \
  } while (0)

  // prologue: tile 0 (leave Ah1(0) in flight)
  STG_B(0, 0, 0); STG_B(0, 1, 0); STG_A(0, 0, 0); STG_A(0, 1, 0);
  asm volatile("s_waitcnt vmcnt(2)" ::: "memory");
  __builtin_amdgcn_s_barrier();

  const int rswz = (l15 & 7) << 4;
  const int bro = ((wn & 1) * 64 + l15) * 128;   // B col-row base (ni added below)

  for (int kt = 0; kt < 16; ++kt) {
    const char* Ab = Asp + (kt & 1) * 32768;
    const char* Bb = Bsp + (kt & 1) * 32768 + (wn >> 1) * 16384;
    const int nkt = kt + 1, nb_ = nkt & 1;
    bf16x8 b0[4], b1[4];

    // ---- phase 0: (m-even, ks0)
    {
      const int cs = (lg * 16) ^ rswz;
      bf16x8 a[4];
      #pragma unroll
      for (int ni = 0; ni < 4; ++ni)
        b0[ni] = *(const bf16x8*)(Bb + bro + ni * 16 * 128 + cs);
      #pragma unroll
      for (int q = 0; q < 4; ++q)
        a[q] = *(const bf16x8*)(Ab + ((wm * 4 + q) * 16 + l15) * 128 + cs);
      if (nkt < 16) STG_B(nb_, 0, nkt);
      __builtin_amdgcn_s_barrier();
      asm volatile("s_waitcnt lgkmcnt(0)" ::: "memory");
      __builtin_amdgcn_s_setprio(1);
      #pragma unroll
      for (int q = 0; q < 4; ++q)
        #pragma unroll
        for (int ni = 0; ni < 4; ++ni)
          acc[2 * q][ni] = __builtin_amdgcn_mfma_f32_16x16x32_bf16(
              a[q], b0[ni], acc[2 * q][ni], 0, 0, 0);
      __builtin_amdgcn_s_setprio(0);
      __builtin_amdgcn_s_barrier();
    }
    // ---- phase 1: (m-even, ks1)
    {
      const int cs = (64 + lg * 16) ^ rswz;
      bf16x8 a[4];
      #pragma unroll
      for (int ni = 0; ni < 4; ++ni)
        b1[ni] = *(const bf16x8*)(Bb + bro + ni * 16 * 128 + cs);
      #pragma unroll
      for (int q = 0; q < 4; ++q)
        a[q] = *(const bf16x8*)(Ab + ((wm * 4 + q) * 16 + l15) * 128 + cs);
      if (nkt < 16) STG_B(nb_, 1, nkt);
      __builtin_amdgcn_s_barrier();
      asm volatile("s_waitcnt lgkmcnt(0)" ::: "memory");
      __builtin_amdgcn_s_setprio(1);
      #pragma unroll
      for (int q = 0; q < 4; ++q)
        #pragma unroll
        for (int ni = 0; ni < 4; ++ni)
          acc[2 * q][ni] = __builtin_amdgcn_mfma_f32_16x16x32_bf16(
              a[q], b1[ni], acc[2 * q][ni], 0, 0, 0);
      __builtin_amdgcn_s_setprio(0);
      if (kt == 15) asm volatile("s_waitcnt vmcnt(0)" ::: "memory");
      else          asm volatile("s_waitcnt vmcnt(4)" ::: "memory");
      __builtin_amdgcn_s_barrier();
    }
    // ---- phase 2: (m-odd, ks0)
    {
      const int cs = (lg * 16) ^ rswz;
      bf16x8 a[4];
      #pragma unroll
      for (int q = 0; q < 4; ++q)
        a[q] = *(const bf16x8*)(Ab + 16384 + ((wm * 4 + q) * 16 + l15) * 128 + cs);
      if (nkt < 16) STG_A(nb_, 0, nkt);
      __builtin_amdgcn_s_barrier();
      asm volatile("s_waitcnt lgkmcnt(0)" ::: "memory");
      __builtin_amdgcn_s_setprio(1);
      #pragma unroll
      for (int q = 0; q < 4; ++q)
        #pragma unroll
        for (int ni = 0; ni < 4; ++ni)
          acc[2 * q + 1][ni] = __builtin_amdgcn_mfma_f32_16x16x32_bf16(
              a[q], b0[ni], acc[2 * q + 1][ni], 0, 0, 0);
      __builtin_amdgcn_s_setprio(0);
      __builtin_amdgcn_s_barrier();
    }
    // ---- phase 3: (m-odd, ks1)
    {
      const int cs = (64 + lg * 16) ^ rswz;
      bf16x8 a[4];
      #pragma unroll
      for (int q = 0; q < 4; ++q)
        a[q] = *(const bf16x8*)(Ab + 16384 + ((wm * 4 + q) * 16 + l15) * 128 + cs);
      if (nkt < 16) STG_A(nb_, 1, nkt);
      __builtin_amdgcn_s_barrier();
      asm volatile("s_waitcnt lgkmcnt(0)" ::: "memory");
      __builtin_amdgcn_s_setprio(1);
      #pragma unroll
      for (int q = 0; q < 4; ++q)
        #pragma unroll
        for (int ni = 0; ni < 4; ++ni)
          acc[2 * q + 1][ni] = __builtin_amdgcn_mfma_f32_16x16x32_bf16(
              a[q], b1[ni], acc[2 * q + 1][ni], 0, 0, 0);
      __builtin_amdgcn_s_setprio(0);
      if (kt < 15) asm volatile("s_waitcnt vmcnt(2)" ::: "memory");
      __builtin_amdgcn_s_barrier();
    }
  }
#undef STG_A
#undef STG_B
}

// chunk-XOR for the epilogue transpose: 16B chunk c -> c ^ (c>>3), bijective.
__device__ __forceinline__ int xchunk4(int colf) {
  int c = colf >> 2;
  return ((c ^ (c >> 3)) << 2) | (colf & 3);
}

// ---------------------------------------------------------------------------
// Phase 1: [K|Q] = x @ Wkqv[h][:, :2048] + b for 8 heads. 256^2 core.
// ---------------------------------------------------------------------------
__global__ __launch_bounds__(512)
void kqv256(const bf16_t* __restrict__ xb, const bf16_t* __restrict__ Wt,
            const float* __restrict__ bkqv, int h0,
            bf16_t* __restrict__ Kc, bf16_t* __restrict__ Qc) {
  __shared__ bf16_t lds[65536];
  const int bid = blockIdx.x;
  const int lid = (bid & 7) * 128 + (bid >> 3);
  const int mb = lid & 15, nb = (lid >> 4) & 7, hz = lid >> 7;

  f32x4 acc[8][4] = {};
  mm256_core(xb + (size_t)mb * 256 * D_,
             Wt + ((size_t)hz * 2048 + (size_t)nb * 256) * D_, lds, acc);

  const int t = threadIdx.x;
  const int w = t >> 6, l = t & 63, l15 = l & 15, lg = l >> 4;
  const int wm = w >> 2, wn = w & 3;
  const int h = h0 + hz;

  float bias[4];
  #pragma unroll
  for (int ni = 0; ni < 4; ++ni)
    bias[ni] = bkqv[h * E_ + nb * 256 + wn * 64 + ni * 16 + l15];
  #pragma unroll
  for (int mi = 0; mi < 8; ++mi)
    #pragma unroll
    for (int ni = 0; ni < 4; ++ni)
      #pragma unroll
      for (int r = 0; r < 4; ++r) acc[mi][ni][r] += bias[ni];

  float* Ct = (float*)lds;   // [64][258], cols chunk-XOR swizzled
  const int cpair = t & 31;
  const int p0 = xchunk4(cpair * 8);
  const int p1 = xchunk4(cpair * 8 + 4);
  #pragma unroll
  for (int s = 0; s < 4; ++s) {
    __syncthreads();
    #pragma unroll
    for (int m2 = 0; m2 < 2; ++m2)
      #pragma unroll
      for (int ni = 0; ni < 4; ++ni)
        #pragma unroll
        for (int r = 0; r < 4; ++r)
          Ct[(wm * 32 + m2 * 16 + lg * 4 + r) * 258 +
             xchunk4(wn * 64 + ni * 16 + l15)] = acc[2 * s + m2][ni][r];
    __syncthreads();
    #pragma unroll
    for (int it = 0; it < 4; ++it) {
      int row64 = (t >> 5) + it * 16;
      int wmq = row64 >> 5, m2q = (row64 >> 4) & 1, r16 = row64 & 15;
      int c8 = cpair * 8;
      const float* r0 = &Ct[row64 * 258 + p0];
      const float* r1 = &Ct[row64 * 258 + p1];
      bf16x8 o = {(bf16_t)r0[0], (bf16_t)r0[1], (bf16_t)r0[2], (bf16_t)r0[3],
                  (bf16_t)r1[0], (bf16_t)r1[1], (bf16_t)r1[2], (bf16_t)r1[3]};
      int grow = mb * 256 + wmq * 128 + (2 * s + m2q) * 16 + r16;
      int b = grow >> 10, n = grow & (N_ - 1);
      int bhl = b * 8 + hz;
      size_t base = ((size_t)bhl * N_ + n) * D_;
      if (nb < 4)
        *(bf16x8*)(Kc + base + nb * 256 + c8) = o;
      else
        *(bf16x8*)(Qc + base + nb * 256 - 1024 + c8) = o;
    }
  }
}

// ---------------------------------------------------------------------------
// Phase 2a: S = scale * Q.K^T, lower-triangle 256x256 tiles (10 per bh).
// ---------------------------------------------------------------------------
__global__ __launch_bounds__(512)
void s_gemm256(const bf16_t* __restrict__ Qc, const bf16_t* __restrict__ Kc,
               float* __restrict__ SgC) {
  __shared__ bf16_t lds[65536];
  const int bid = blockIdx.x;
  const int lid = (bid & 7) * 40 + (bid >> 3);
  const int idx = lid % 10;
  const int bhl = lid / 10;
  int qt = 0;
  while ((qt + 1) * (qt + 2) / 2 <= idx) ++qt;
  const int kt = idx - qt * (qt + 1) / 2;

  f32x4 acc[8][4] = {};
  mm256_core(Qc + ((size_t)bhl * N_ + (size_t)qt * 256) * D_,
             Kc + ((size_t)bhl * N_ + (size_t)kt * 256) * D_, lds, acc);

  const int t = threadIdx.x;
  const int w = t >> 6, l = t & 63, l15 = l & 15, lg = l >> 4;
  const int wm = w >> 2, wn = w & 3;
  const float SCALE = 0.045084220027780106f;   // log2(e)/sqrt(1024)
  float* So = SgC + (((size_t)bhl * 10 + idx) << 16);

  #pragma unroll
  for (int mi = 0; mi < 8; ++mi)
    #pragma unroll
    for (int ni = 0; ni < 4; ++ni)
      #pragma unroll
      for (int r = 0; r < 4; ++r) {
        int rl = wm * 128 + mi * 16 + lg * 4 + r;
        int cl = wn * 64 + ni * 16 + l15;
        float z = acc[mi][ni][r] * SCALE;
        if (kt * 256 + cl > qt * 256 + rl) z = -1e30f;
        acc[mi][ni][r] = z;
      }

  float* Ct = (float*)lds;
  const int cpair = t & 31;
  const int p0 = xchunk4(cpair * 8);
  const int p1 = xchunk4(cpair * 8 + 4);
  #pragma unroll
  for (int s = 0; s < 4; ++s) {
    __syncthreads();
    #pragma unroll
    for (int m2 = 0; m2 < 2; ++m2)
      #pragma unroll
      for (int ni = 0; ni < 4; ++ni)
        #pragma unroll
        for (int r = 0; r < 4; ++r)
          Ct[(wm * 32 + m2 * 16 + lg * 4 + r) * 258 +
             xchunk4(wn * 64 + ni * 16 + l15)] = acc[2 * s + m2][ni][r];
    __syncthreads();
    #pragma unroll
    for (int it = 0; it < 4; ++it) {
      int row64 = (t >> 5) + it * 16;
      int wmq = row64 >> 5, m2q = (row64 >> 4) & 1, r16 = row64 & 15;
      int c8 = cpair * 8;
      const float* r0 = &Ct[row64 * 258 + p0];
      const float* r1 = &Ct[row64 * 258 + p1];
      float4 v0 = {r0[0], r0[1], r0[2], r0[3]};
      float4 v1 = {r1[0], r1[1], r1[2], r1[3]};
      int rl = wmq * 128 + (2 * s + m2q) * 16 + r16;
      *(float4*)(So + (size_t)rl * 256 + c8) = v0;
      *(float4*)(So + (size_t)rl * 256 + c8 + 4) = v1;
    }
  }
}

// ---------------------------------------------------------------------------
// V gemm (unchanged)
// ---------------------------------------------------------------------------
__global__ __launch_bounds__(256)
void v_gemm(const bf16_t* __restrict__ xb, const bf16_t* __restrict__ Wvt,
            const float* __restrict__ bkqv, bf16_t* __restrict__ Vt) {
  const int nt = blockIdx.x;
  const int h = blockIdx.y;
  const int t = threadIdx.x;
  const int w = t >> 6, l = t & 63, l15 = l & 15, lg = l >> 4;

  __shared__ bf16_t As2[64 * 64];
  __shared__ bf16_t Bs2[128 * 64];
  const bf16_t* Wvh = Wvt + (size_t)h * DH_ * D_;
  const bf16_t* Bn = xb + (size_t)nt * 128 * D_;

  f32x4 acc[4][2] = {};
  const int rswz = (l15 & 7) << 4;

  for (int kb = 0; kb < 16; ++kb) {
    __syncthreads();
    #pragma unroll
    for (int i = 0; i < 2; ++i) {
      int idx = t + i * 256;
      int row = idx >> 3, c = idx & 7;
      gload_lds16(Wvh + (size_t)row * D_ + kb * 64 + ((c ^ (row & 7)) << 3),
                  (char*)As2 + idx * 16);
    }
    #pragma unroll
    for (int i = 0; i < 4; ++i) {
      int idx = t + i * 256;
      int row = idx >> 3, c = idx & 7;
      gload_lds16(Bn + (size_t)row * D_ + kb * 64 + ((c ^ (row & 7)) << 3),
                  (char*)Bs2 + idx * 16);
    }
    __syncthreads();
    #pragma unroll
    for (int ks = 0; ks < 2; ++ks) {
      const int cswz = (ks * 64 + lg * 16) ^ rswz;
      bf16x8 a[4], b[2];
      #pragma unroll
      for (int mi = 0; mi < 4; ++mi)
        a[mi] = *(const bf16x8*)((const char*)As2 + (mi * 16 + l15) * 128 + cswz);
      #pragma unroll
      for (int ni = 0; ni < 2; ++ni)
        b[ni] = *(const bf16x8*)((const char*)Bs2 + (w * 32 + ni * 16 + l15) * 128 + cswz);
      #pragma unroll
      for (int mi = 0; mi < 4; ++mi)
        #pragma unroll
        for (int ni = 0; ni < 2; ++ni)
          acc[mi][ni] = __builtin_amdgcn_mfma_f32_16x16x32_bf16(a[mi], b[ni], acc[mi][ni], 0, 0, 0);
    }
  }

  #pragma unroll
  for (int mi = 0; mi < 4; ++mi)
    #pragma unroll
    for (int r = 0; r < 4; ++r) {
      int dh = mi * 16 + lg * 4 + r;
      float bias = bkqv[h * E_ + 2048 + dh];
      #pragma unroll
      for (int ni = 0; ni < 2; ++ni) {
        int nn = nt * 128 + w * 32 + ni * 16 + l15;
        int b = nn >> 10, n = nn & (N_ - 1);
        int bh = b * H_ + h;
        Vt[((size_t)bh * DH_ + dh) * N_ + n] = (bf16_t)(acc[mi][ni][r] + bias);
      }
    }
}

// ---------------------------------------------------------------------------
// Phase 2b: softmax + P.V (unchanged)
// ---------------------------------------------------------------------------
__global__ __launch_bounds__(256)
void softmax_pv(const float* __restrict__ SgC, const bf16_t* __restrict__ Vt,
                bf16_t* __restrict__ sa, int c) {
  const int qt = blockIdx.x;
  const int bhl = blockIdx.y;
  const int t = threadIdx.x;
  const int w = t >> 6, l = t & 63, l15 = l & 15, lg = l >> 4;
  const int b = bhl >> 3, h = c * 8 + (bhl & 7);
  const int bh = b * H_ + h;

  const int qrow = qt * 64 + w * 16 + l15;
  const int qt8 = qt >> 2;
  const float* Sbh = SgC + (((size_t)bhl * 10) << 16);
  const bf16_t* Vh = Vt + (size_t)bh * DH_ * N_;

  f32x4 accO[4] = {};
  float m = -1e30f, lsum = 0.f;

  for (int j = 0; j <= qt; ++j) {
    const int jb = j * 64;
    const int tid = qt8 * (qt8 + 1) / 2 + (j >> 2);
    const float* Srow = Sbh + ((size_t)tid << 16) + (size_t)(qrow & 255) * 256 + (jb & 255);

    float4 sA = *(const float4*)(Srow + lg * 8);
    float4 sB = *(const float4*)(Srow + lg * 8 + 4);
    float4 sC = *(const float4*)(Srow + 32 + lg * 8);
    float4 sD = *(const float4*)(Srow + 32 + lg * 8 + 4);

    float zm = fmaxf(fmaxf(fmaxf(sA.x, sA.y), fmaxf(sA.z, sA.w)),
                     fmaxf(fmaxf(sB.x, sB.y), fmaxf(sB.z, sB.w)));
    zm = fmaxf(zm, fmaxf(fmaxf(fmaxf(sC.x, sC.y), fmaxf(sC.z, sC.w)),
                         fmaxf(fmaxf(sD.x, sD.y), fmaxf(sD.z, sD.w))));
    zm = fmaxf(zm, __shfl_xor(zm, 16));
    zm = fmaxf(zm, __shfl_xor(zm, 32));

    float mnew = fmaxf(m, zm);
    float scl = exp2f(m - mnew);
    m = mnew;

    float p[16];
    p[0] = exp2f(sA.x - mnew); p[1] = exp2f(sA.y - mnew);
    p[2] = exp2f(sA.z - mnew); p[3] = exp2f(sA.w - mnew);
    p[4] = exp2f(sB.x - mnew); p[5] = exp2f(sB.y - mnew);
    p[6] = exp2f(sB.z - mnew); p[7] = exp2f(sB.w - mnew);
    p[8] = exp2f(sC.x - mnew); p[9] = exp2f(sC.y - mnew);
    p[10] = exp2f(sC.z - mnew); p[11] = exp2f(sC.w - mnew);
    p[12] = exp2f(sD.x - mnew); p[13] = exp2f(sD.y - mnew);
    p[14] = exp2f(sD.z - mnew); p[15] = exp2f(sD.w - mnew);

    float rs = 0.f;
    #pragma unroll
    for (int i = 0; i < 16; ++i) rs += p[i];
    rs += __shfl_xor(rs, 16);
    rs += __shfl_xor(rs, 32);
    lsum = lsum * scl + rs;

    float sclO[4];
    #pragma unroll
    for (int r = 0; r < 4; ++r) sclO[r] = __shfl(scl, lg * 4 + r);
    #pragma unroll
    for (int db = 0; db < 4; ++db)
      #pragma unroll
      for (int r = 0; r < 4; ++r) accO[db][r] *= sclO[r];

    bf16x8 pa0 = {(bf16_t)p[0], (bf16_t)p[1], (bf16_t)p[2], (bf16_t)p[3],
                  (bf16_t)p[4], (bf16_t)p[5], (bf16_t)p[6], (bf16_t)p[7]};
    bf16x8 pa1 = {(bf16_t)p[8], (bf16_t)p[9], (bf16_t)p[10], (bf16_t)p[11],
                  (bf16_t)p[12], (bf16_t)p[13], (bf16_t)p[14], (bf16_t)p[15]};

    #pragma unroll
    for (int db = 0; db < 4; ++db) {
      const bf16_t* vp = Vh + (size_t)(db * 16 + l15) * N_ + jb;
      bf16x8 vb0 = *(const bf16x8*)(vp + lg * 8);
      bf16x8 vb1 = *(const bf16x8*)(vp + 32 + lg * 8);
      accO[db] = __builtin_amdgcn_mfma_f32_16x16x32_bf16(pa0, vb0, accO[db], 0, 0, 0);
      accO[db] = __builtin_amdgcn_mfma_f32_16x16x32_bf16(pa1, vb1, accO[db], 0, 0, 0);
    }
  }

  float lO[4];
  #pragma unroll
  for (int r = 0; r < 4; ++r) lO[r] = __shfl(lsum, lg * 4 + r);

  #pragma unroll
  for (int db = 0; db < 4; ++db)
    #pragma unroll
    for (int r = 0; r < 4; ++r) {
      int row = qt * 64 + w * 16 + lg * 4 + r;
      int col = h * DH_ + db * 16 + l15;
      sa[((size_t)b * N_ + row) * D_ + col] = (bf16_t)(accO[db][r] / lO[r]);
    }
}

// ---------------------------------------------------------------------------
// Phase 3: out = sa @ Wp + bp (m97 128^2 structure, fp32 out)
// ---------------------------------------------------------------------------
__global__ __launch_bounds__(256)
void out_gemm(const bf16_t* __restrict__ A, const bf16_t* __restrict__ Bt,
              const float* __restrict__ bp, float* __restrict__ out) {
  const int mb = blockIdx.x, nb = blockIdx.y;
  const int t = threadIdx.x;
  const int w = t >> 6, l = t & 63, l15 = l & 15, lg = l >> 4;
  const int wr = (w >> 1) * 64, wc = (w & 1) * 64;

  __shared__ bf16_t As[128 * 64];
  __shared__ bf16_t Bs[128 * 64];

  const int srow = w * 32 + (l >> 3);
  const int scol = (l & 7) * 8;
  const bf16_t* ag = A + (size_t)(mb * 128 + srow) * D_ + scol;
  const bf16_t* bg = Bt + (size_t)(nb * 128 + srow) * D_ + scol;
  char* asl = (char*)As + w * 4096;
  char* bsl = (char*)Bs + w * 4096;

  f32x4 acc[4][4] = {};

  for (int kb = 0; kb < 16; ++kb) {
    __syncthreads();
    #pragma unroll
    for (int i = 0; i < 4; ++i) {
      gload_lds16(ag + (size_t)i * 8 * D_ + kb * 64, asl + i * 1024);
      gload_lds16(bg + (size_t)i * 8 * D_ + kb * 64, bsl + i * 1024);
    }
    __syncthreads();
    #pragma unroll
    for (int ks = 0; ks < 2; ++ks) {
      bf16x8 a[4], b[4];
      #pragma unroll
      for (int mi = 0; mi < 4; ++mi)
        a[mi] = *(const bf16x8*)((const char*)As + (wr + mi * 16 + l15) * 128 + ks * 64 + lg * 16);
      #pragma unroll
      for (int ni = 0; ni < 4; ++ni)
        b[ni] = *(const bf16x8*)((const char*)Bs + (wc + ni * 16 + l15) * 128 + ks * 64 + lg * 16);
      #pragma unroll
      for (int mi = 0; mi < 4; ++mi)
        #pragma unroll
        for (int ni = 0; ni < 4; ++ni)
          acc[mi][ni] = __builtin_amdgcn_mfma_f32_16x16x32_bf16(a[mi], b[ni], acc[mi][ni], 0, 0, 0);
    }
  }

  #pragma unroll
  for (int ni = 0; ni < 4; ++ni) {
    int e = nb * 128 + wc + ni * 16 + l15;
    float bias = bp[e];
    #pragma unroll
    for (int mi = 0; mi < 4; ++mi)
      #pragma unroll
      for (int r = 0; r < 4; ++r) {
        int grow = mb * 128 + wr + mi * 16 + lg * 4 + r;
        out[(size_t)grow * D_ + e] = acc[mi][ni][r] + bias;
      }
  }
}

// ---------------------------------------------------------------------------
extern "C" void kernel_launch(void* const* d_in, const int* in_sizes, int n_in,
                              void* d_out, int out_size, void* d_ws, size_t ws_size,
                              hipStream_t stream) {
  const float* x    = (const float*)d_in[0];
  const float* Wkqv = (const float*)d_in[1];
  const float* bkqv = (const float*)d_in[2];
  const float* Wp   = (const float*)d_in[3];
  const float* bp   = (const float*)d_in[4];
  float* out = (float*)d_out;
  char* ws = (char*)d_ws;

  const size_t MB = 1 << 20;
  bf16_t* xb  = (bf16_t*)(ws);             //   8 MiB
  bf16_t* sa  = (bf16_t*)(ws + 8 * MB);    //   8 MiB
  bf16_t* Wpt = (bf16_t*)(ws + 16 * MB);   //   2 MiB
  bf16_t* Vt  = (bf16_t*)(ws + 18 * MB);   //   8 MiB
  bf16_t* Qc  = (bf16_t*)(ws + 26 * MB);   //  64 MiB (32 bh)
  bf16_t* Kc  = (bf16_t*)(ws + 90 * MB);   //  64 MiB (32 bh)
  bf16_t* Wt  = (bf16_t*)(ws + 154 * MB);  //  32 MiB (8 heads)
  bf16_t* Wvt = (bf16_t*)(ws + 186 * MB);  //   2 MiB
  float*  SgC = (float*) (ws + 188 * MB);  //  80 MiB
  // total 268 MiB (< proven-safe 285,212,672 B)

  hipLaunchKernelGGL(conv_x, dim3(1024), dim3(256), 0, stream, x, xb);
  hipLaunchKernelGGL(conv_wp, dim3(32, 32), dim3(256), 0, stream, Wp, Wpt);
  hipLaunchKernelGGL(conv_wv, dim3(2, 32, 16), dim3(256), 0, stream, Wkqv, Wvt);
  hipLaunchKernelGGL(v_gemm, dim3(32, 16), dim3(256), 0, stream, xb, Wvt, bkqv, Vt);

  for (int c = 0; c < 2; ++c) {
    hipLaunchKernelGGL(conv_wkqv, dim3(32, 16, 8), dim3(256), 0, stream,
                       Wkqv, Wt, c * 8);
    hipLaunchKernelGGL(kqv256, dim3(1024), dim3(512), 0, stream,
                       xb, Wt, bkqv, c * 8, Kc, Qc);
    hipLaunchKernelGGL(s_gemm256, dim3(320), dim3(512), 0, stream,
                       Qc, Kc, SgC);
    hipLaunchKernelGGL(softmax_pv, dim3(16, 32), dim3(256), 0, stream,
                       SgC, Vt, sa, c);
  }

  hipLaunchKernelGGL(out_gemm, dim3(32, 8), dim3(256), 0, stream, sa, Wpt, bp, out);
}